// Round 1
// baseline (3005.301 us; speedup 1.0000x reference)
//
#include <hip/hip_runtime.h>
#include <hip/hip_bf16.h>

#define H_HEADS 16
#define DH 128
#define SLEN 1024
#define BATCH 4
#define DMODEL 2048

// ---------------- f32 tiled GEMM: C[M][N] = A[M][K] @ B[K][N] ----------------
// 128x128 block tile, BK=8, 256 threads, 8x8 per-thread microtile.
template<int BK>
__global__ __launch_bounds__(256) void gemm_f32(const float* __restrict__ A,
                                                const float* __restrict__ B,
                                                float* __restrict__ C,
                                                int M, int N, int K)
{
    __shared__ float As[BK][128];   // transposed: As[k][m]
    __shared__ float Bs[BK][128];   // Bs[k][n]
    const int tid = threadIdx.x;
    const int bn = blockIdx.x * 128;
    const int bm = blockIdx.y * 128;
    const int tx = tid & 15, ty = tid >> 4;

    float acc[8][8];
#pragma unroll
    for (int i = 0; i < 8; ++i)
#pragma unroll
        for (int j = 0; j < 8; ++j) acc[i][j] = 0.f;

    const int arow = tid >> 1, akq = (tid & 1) * 4;   // A: 128 rows x 8 k
    const int bkr = tid >> 5, bcol = (tid & 31) * 4;  // B: 8 k x 128 n

    for (int k0 = 0; k0 < K; k0 += BK) {
        float4 av = *(const float4*)&A[(size_t)(bm + arow) * K + k0 + akq];
        float4 bv = *(const float4*)&B[(size_t)(k0 + bkr) * N + bn + bcol];
        As[akq + 0][arow] = av.x;
        As[akq + 1][arow] = av.y;
        As[akq + 2][arow] = av.z;
        As[akq + 3][arow] = av.w;
        *(float4*)&Bs[bkr][bcol] = bv;
        __syncthreads();
#pragma unroll
        for (int kk = 0; kk < BK; ++kk) {
            float4 a0 = *(const float4*)&As[kk][ty * 8];
            float4 a1 = *(const float4*)&As[kk][ty * 8 + 4];
            float4 b0 = *(const float4*)&Bs[kk][tx * 8];
            float4 b1 = *(const float4*)&Bs[kk][tx * 8 + 4];
            float a[8]  = {a0.x, a0.y, a0.z, a0.w, a1.x, a1.y, a1.z, a1.w};
            float bb[8] = {b0.x, b0.y, b0.z, b0.w, b1.x, b1.y, b1.z, b1.w};
#pragma unroll
            for (int i = 0; i < 8; ++i)
#pragma unroll
                for (int j = 0; j < 8; ++j) acc[i][j] += a[i] * bb[j];
        }
        __syncthreads();
    }

#pragma unroll
    for (int i = 0; i < 8; ++i) {
        float4 c0 = {acc[i][0], acc[i][1], acc[i][2], acc[i][3]};
        float4 c1 = {acc[i][4], acc[i][5], acc[i][6], acc[i][7]};
        size_t off = (size_t)(bm + ty * 8 + i) * N + bn + tx * 8;
        *(float4*)&C[off]     = c0;
        *(float4*)&C[off + 4] = c1;
    }
}

// --------- fused RMSNorm + RoPE, in-place on qkv[B,S,3,H,DH] (q and k) -------
// One 64-thread wave per (b,s,h,comp). Lane p owns dims 2p, 2p+1 (a RoPE pair).
__global__ __launch_bounds__(64) void rmsrope(float* __restrict__ qkv,
                                              const float* __restrict__ pe,
                                              const float* __restrict__ q_scale,
                                              const float* __restrict__ q_bias,
                                              const float* __restrict__ k_scale,
                                              const float* __restrict__ k_bias)
{
    const int bid  = blockIdx.x;            // bs*32 + h*2 + comp
    const int l    = threadIdx.x;           // 0..63 pair index
    const int bs   = bid >> 5;              // 0..4095 (= b*S + s)
    const int h    = (bid >> 1) & 15;
    const int comp = bid & 1;               // 0 = q, 1 = k

    float* base = qkv + ((size_t)bs * 3 + comp) * DMODEL + h * DH;
    const float* scale = comp ? k_scale : q_scale;
    const float* bias  = comp ? k_bias  : q_bias;

    float u0 = base[2 * l], u1 = base[2 * l + 1];
    float ss = u0 * u0 + u1 * u1;
#pragma unroll
    for (int o = 32; o; o >>= 1) ss += __shfl_xor(ss, o);
    float inv = rsqrtf(ss * (1.f / DH) + 1e-6f);

    float a = u0 * inv * scale[2 * l]     + bias[2 * l];
    float c = u1 * inv * scale[2 * l + 1] + bias[2 * l + 1];

    // pe[b,s,0,p,i,j] flat: bs*256 + p*4 + i*2 + j
    float4 p4 = *(const float4*)(pe + (size_t)bs * 256 + l * 4);
    base[2 * l]     = p4.x * a + p4.y * c;  // i=0
    base[2 * l + 1] = p4.z * a + p4.w * c;  // i=1
}

// ------------- flash-style f32 attention, full (non-causal), scale=1/sqrt(DH)
// Block: 256 threads = 64 q-rows x 4 threads (each owns 32 of 128 dims).
// K/V chunks of 32 rows staged in LDS; online softmax kept in registers
// (redundantly computed by the 4 lanes of each quad).
__global__ __launch_bounds__(256) void attn_f32(const float* __restrict__ qkv,
                                                float* __restrict__ out)
{
    __shared__ float K_lds[32][128];
    __shared__ float V_lds[32][128];
    const int tid  = threadIdx.x;
    const int bidx = blockIdx.x;        // b*256 + h*16 + qt
    const int qt = bidx & 15;
    const int h  = (bidx >> 4) & 15;
    const int b  = bidx >> 8;

    const int qr = tid >> 2, g = tid & 3;
    const int srow = qt * 64 + qr;

    const float* qp = qkv + ((size_t)(b * SLEN + srow) * 3) * DMODEL + h * DH + g * 32;
    float qf[32];
#pragma unroll
    for (int t = 0; t < 8; ++t) {
        float4 v = *(const float4*)(qp + 4 * t);
        qf[4 * t] = v.x; qf[4 * t + 1] = v.y; qf[4 * t + 2] = v.z; qf[4 * t + 3] = v.w;
    }

    float m = -1e30f, lsum = 0.f;
    float acc[32];
#pragma unroll
    for (int j = 0; j < 32; ++j) acc[j] = 0.f;

    const int krow = tid >> 3, kcb = (tid & 7) * 16;

    for (int kc = 0; kc < SLEN; kc += 32) {
        __syncthreads();
        const float* kp = qkv + ((size_t)(b * SLEN + kc + krow) * 3 + 1) * DMODEL + h * DH + kcb;
        const float* vp = kp + DMODEL;  // comp 2
#pragma unroll
        for (int t = 0; t < 4; ++t) {
            *(float4*)&K_lds[krow][kcb + 4 * t] = *(const float4*)(kp + 4 * t);
            *(float4*)&V_lds[krow][kcb + 4 * t] = *(const float4*)(vp + 4 * t);
        }
        __syncthreads();

        float sc[32];
#pragma unroll
        for (int kk = 0; kk < 32; ++kk) {
            const float4* k4 = (const float4*)&K_lds[kk][g * 32];
            float s = 0.f;
#pragma unroll
            for (int t = 0; t < 8; ++t) {
                float4 kv = k4[t];
                s += qf[4 * t] * kv.x + qf[4 * t + 1] * kv.y
                   + qf[4 * t + 2] * kv.z + qf[4 * t + 3] * kv.w;
            }
            s += __shfl_xor(s, 1);
            s += __shfl_xor(s, 2);
            sc[kk] = s * 0.08838834764831845f;  // 1/sqrt(128)
        }

        float mc = sc[0];
#pragma unroll
        for (int kk = 1; kk < 32; ++kk) mc = fmaxf(mc, sc[kk]);
        float mn = fmaxf(m, mc);
        float alpha = __expf(m - mn);
        lsum *= alpha;
#pragma unroll
        for (int j = 0; j < 32; ++j) acc[j] *= alpha;
        float ls = 0.f;
#pragma unroll
        for (int kk = 0; kk < 32; ++kk) {
            float e = __expf(sc[kk] - mn);
            sc[kk] = e;
            ls += e;
        }
        lsum += ls;
        m = mn;

#pragma unroll
        for (int kk = 0; kk < 32; ++kk) {
            float p = sc[kk];
            const float4* v4 = (const float4*)&V_lds[kk][g * 32];
#pragma unroll
            for (int t = 0; t < 8; ++t) {
                float4 vv = v4[t];
                acc[4 * t]     += p * vv.x;
                acc[4 * t + 1] += p * vv.y;
                acc[4 * t + 2] += p * vv.z;
                acc[4 * t + 3] += p * vv.w;
            }
        }
    }

    float invl = 1.f / lsum;
    float* op = out + (size_t)(b * SLEN + srow) * DMODEL + h * DH + g * 32;
#pragma unroll
    for (int t = 0; t < 8; ++t) {
        float4 v = {acc[4 * t] * invl, acc[4 * t + 1] * invl,
                    acc[4 * t + 2] * invl, acc[4 * t + 3] * invl};
        *(float4*)(op + 4 * t) = v;
    }
}

extern "C" void kernel_launch(void* const* d_in, const int* in_sizes, int n_in,
                              void* d_out, int out_size, void* d_ws, size_t ws_size,
                              hipStream_t stream) {
    const float* x       = (const float*)d_in[0];
    const float* pe      = (const float*)d_in[1];
    const float* w_qkv   = (const float*)d_in[2];
    const float* w_o     = (const float*)d_in[3];
    const float* q_scale = (const float*)d_in[4];
    const float* q_bias  = (const float*)d_in[5];
    const float* k_scale = (const float*)d_in[6];
    const float* k_bias  = (const float*)d_in[7];
    float* out = (float*)d_out;

    float* qkv     = (float*)d_ws;                       // [4096][3*2048] f32 = 100.7 MB
    float* attnbuf = qkv + (size_t)4096 * 3 * DMODEL;    // [4096][2048]  f32 = 33.6 MB

    // 1) qkv = x @ w_qkv   (M=4096, N=6144, K=2048)
    gemm_f32<8><<<dim3(6144 / 128, 4096 / 128), 256, 0, stream>>>(
        x, w_qkv, qkv, 4096, 6144, 2048);

    // 2) RMSNorm + RoPE in-place on q and k
    rmsrope<<<dim3(4096 * 32), 64, 0, stream>>>(qkv, pe, q_scale, q_bias, k_scale, k_bias);

    // 3) attention -> attnbuf [B,S,D]
    attn_f32<<<dim3(BATCH * H_HEADS * (SLEN / 64)), 256, 0, stream>>>(qkv, attnbuf);

    // 4) out = attnbuf @ w_o  (M=4096, N=2048, K=2048)
    gemm_f32<8><<<dim3(2048 / 128, 4096 / 128), 256, 0, stream>>>(
        attnbuf, w_o, out, 4096, 2048, 2048);
}

// Round 2
// 400.958 us; speedup vs baseline: 7.4953x; 7.4953x over previous
//
#include <hip/hip_runtime.h>
#include <hip/hip_bf16.h>

typedef _Float16 f16_t;
typedef _Float16 f16x2 __attribute__((ext_vector_type(2)));
typedef _Float16 f16x4 __attribute__((ext_vector_type(4)));
typedef _Float16 f16x8 __attribute__((ext_vector_type(8)));
typedef float f32x4 __attribute__((ext_vector_type(4)));

#define GLOAD_LDS16(gp, lp)                                                        \
  __builtin_amdgcn_global_load_lds(                                                \
      (const __attribute__((address_space(1))) void*)(gp),                         \
      (__attribute__((address_space(3))) void*)(lp), 16, 0, 0)

// ---------------- f32 -> f16 elementwise convert (8 elems/thread) ----------------
__global__ __launch_bounds__(256) void conv_f16(const float* __restrict__ in,
                                                f16_t* __restrict__ out)
{
    int i = blockIdx.x * 256 + threadIdx.x;
    float4 a = *(const float4*)&in[(size_t)i * 8];
    float4 b = *(const float4*)&in[(size_t)i * 8 + 4];
    f16x8 o = {(f16_t)a.x, (f16_t)a.y, (f16_t)a.z, (f16_t)a.w,
               (f16_t)b.x, (f16_t)b.y, (f16_t)b.z, (f16_t)b.w};
    *(f16x8*)&out[(size_t)i * 8] = o;
}

// ------------- f32 [R][C] -> f16 transposed [C][R], 32x32 LDS tiles -------------
__global__ __launch_bounds__(256) void transpose_f16(const float* __restrict__ in,
                                                     f16_t* __restrict__ out,
                                                     int R, int C)
{
    __shared__ float t[32][33];
    const int tr = blockIdx.y, tc = blockIdx.x;
    const int r = threadIdx.x >> 3, c4 = (threadIdx.x & 7) * 4;
    float4 v = *(const float4*)&in[(size_t)(tr * 32 + r) * C + tc * 32 + c4];
    t[r][c4 + 0] = v.x; t[r][c4 + 1] = v.y; t[r][c4 + 2] = v.z; t[r][c4 + 3] = v.w;
    __syncthreads();
    f16x4 o = {(f16_t)t[c4 + 0][r], (f16_t)t[c4 + 1][r],
               (f16_t)t[c4 + 2][r], (f16_t)t[c4 + 3][r]};
    *(f16x4*)&out[(size_t)(tc * 32 + r) * R + tr * 32 + c4] = o;
}

// ---------------- f16 MFMA GEMM: C = A[M][K] @ BT[N][K]^T ----------------
// 128x128 tile, BK=32, 4 waves x (4x4 16x16x32 fragments). global_load_lds staging.
template<int F16OUT>
__global__ __launch_bounds__(256) void gemm_f16(const f16_t* __restrict__ A,
                                                const f16_t* __restrict__ BT,
                                                void* __restrict__ Cout,
                                                int M, int N, int K, int gx)
{
    __shared__ f16_t Asl[128 * 32];
    __shared__ f16_t Bsl[128 * 32];
    const int tid = threadIdx.x, lane = tid & 63, wave = tid >> 6;
    const int lh = lane >> 4, li = lane & 15;
    const int wr = wave >> 1, wc = wave & 1;

    // XCD-bijective swizzle (nwg % 8 == 0 for all our grids)
    const int nwg = gridDim.x;
    const int bid = blockIdx.x;
    const int swz = (bid & 7) * (nwg >> 3) + (bid >> 3);
    const int bx = swz % gx, by = swz / gx;

    const size_t bmK = (size_t)(by * 128) * K;
    const size_t bnK = (size_t)(bx * 128) * K;

    f32x4 acc[4][4];
#pragma unroll
    for (int i = 0; i < 4; ++i)
#pragma unroll
        for (int j = 0; j < 4; ++j) acc[i][j] = (f32x4){0.f, 0.f, 0.f, 0.f};

    for (int k0 = 0; k0 < K; k0 += 32) {
        __syncthreads();
#pragma unroll
        for (int it = 0; it < 2; ++it) {
            const int c = it * 256 + tid;
            const int row = c >> 2, kb = (c & 3) << 3;
            const int ldsoff = (it * 256 + wave * 64) * 16;  // bytes, wave-uniform
            GLOAD_LDS16(A + bmK + (size_t)row * K + k0 + kb, (char*)Asl + ldsoff);
            GLOAD_LDS16(BT + bnK + (size_t)row * K + k0 + kb, (char*)Bsl + ldsoff);
        }
        __syncthreads();
        f16x8 af[4], bf[4];
#pragma unroll
        for (int mi = 0; mi < 4; ++mi)
            af[mi] = *(const f16x8*)(Asl + (wr * 64 + mi * 16 + li) * 32 + lh * 8);
#pragma unroll
        for (int ni = 0; ni < 4; ++ni)
            bf[ni] = *(const f16x8*)(Bsl + (wc * 64 + ni * 16 + li) * 32 + lh * 8);
#pragma unroll
        for (int mi = 0; mi < 4; ++mi)
#pragma unroll
            for (int ni = 0; ni < 4; ++ni)
                acc[mi][ni] = __builtin_amdgcn_mfma_f32_16x16x32_f16(af[mi], bf[ni],
                                                                     acc[mi][ni], 0, 0, 0);
    }

    // C/D layout: col = lane&15, row = (lane>>4)*4 + reg
#pragma unroll
    for (int mi = 0; mi < 4; ++mi)
#pragma unroll
        for (int ni = 0; ni < 4; ++ni)
#pragma unroll
            for (int r = 0; r < 4; ++r) {
                const int row = by * 128 + wr * 64 + mi * 16 + lh * 4 + r;
                const int col = bx * 128 + wc * 64 + ni * 16 + li;
                if (F16OUT)
                    ((f16_t*)Cout)[(size_t)row * N + col] = (f16_t)acc[mi][ni][r];
                else
                    ((float*)Cout)[(size_t)row * N + col] = acc[mi][ni][r];
            }
}

// --------- fused RMSNorm + RoPE in-place on f16 qkv[B*S][3][16][128] ---------
__global__ __launch_bounds__(256) void rmsrope_f16(f16_t* __restrict__ qkv,
                                                   const float* __restrict__ pe,
                                                   const float* __restrict__ qs,
                                                   const float* __restrict__ qb,
                                                   const float* __restrict__ ks,
                                                   const float* __restrict__ kb)
{
    const int unit = blockIdx.x * 4 + (threadIdx.x >> 6);  // bs*32 + h*2 + comp
    const int l = threadIdx.x & 63;
    const int bs = unit >> 5, h = (unit >> 1) & 15, comp = unit & 1;
    f16_t* base = qkv + ((size_t)bs * 3 + comp) * 2048 + h * 128;
    const float* sc = comp ? ks : qs;
    const float* bi = comp ? kb : qb;

    f16x2 u = *(const f16x2*)(base + 2 * l);
    float u0 = (float)u[0], u1 = (float)u[1];
    float ss = u0 * u0 + u1 * u1;
#pragma unroll
    for (int o = 32; o; o >>= 1) ss += __shfl_xor(ss, o);
    float inv = rsqrtf(ss * (1.f / 128.f) + 1e-6f);

    float2 scv = *(const float2*)(sc + 2 * l);
    float2 biv = *(const float2*)(bi + 2 * l);
    float a = u0 * inv * scv.x + biv.x;
    float c = u1 * inv * scv.y + biv.y;
    float4 p4 = *(const float4*)(pe + (size_t)bs * 256 + l * 4);
    f16x2 o = {(f16_t)(p4.x * a + p4.y * c), (f16_t)(p4.z * a + p4.w * c)};
    *(f16x2*)(base + 2 * l) = o;
}

// ---------------- flash attention, f16 MFMA, swapped QK^T ----------------
// 4 waves/block; wave owns 16 q rows; KV blocks of 32.
__global__ __launch_bounds__(256) void attn_f16(const f16_t* __restrict__ qkv,
                                                f16_t* __restrict__ out)
{
    __shared__ f16_t Kl[32 * 128];
    __shared__ f16_t Vt[128 * 34];   // transposed V, pad to 34 (b32-read conflict-free)
    const int tid = threadIdx.x, lane = tid & 63, wave = tid >> 6;
    const int lh = lane >> 4, li = lane & 15;
    const int bidx = blockIdx.x;
    const int qt = bidx & 15, h = (bidx >> 4) & 15, b = bidx >> 8;
    const size_t seqbase = (size_t)b * 1024;
    const float SCALE = 0.08838834764831845f;  // 1/sqrt(128)

    // Q hoist: lane (lh, li) holds Q[qrow(li)][d = c*32 + lh*8 + j]
    const int qrow = qt * 64 + wave * 16 + li;
    f16x8 qreg[4];
    {
        const f16_t* qp = qkv + (seqbase + qrow) * 3 * 2048 + h * 128;
#pragma unroll
        for (int c = 0; c < 4; ++c)
            qreg[c] = *(const f16x8*)(qp + c * 32 + lh * 8);
    }

    f32x4 oacc[8];
#pragma unroll
    for (int dt = 0; dt < 8; ++dt) oacc[dt] = (f32x4){0.f, 0.f, 0.f, 0.f};
    float mrun = -1e30f, lrun = 0.f;

    for (int kc = 0; kc < 1024; kc += 32) {
        __syncthreads();
        // stage K rows [32][128] linear via global_load_lds
#pragma unroll
        for (int it = 0; it < 2; ++it) {
            const int c = it * 256 + tid;
            const int row = c >> 4, db = (c & 15) << 3;
            const int ldsoff = (it * 256 + wave * 64) * 16;
            GLOAD_LDS16(qkv + (seqbase + kc + row) * 3 * 2048 + 2048 + h * 128 + db,
                        (char*)Kl + ldsoff);
        }
        // stage V transposed via registers
        f16x8 vst[2]; int vkv[2], vdb[2];
#pragma unroll
        for (int it = 0; it < 2; ++it) {
            const int c = it * 256 + tid;
            vkv[it] = c >> 4; vdb[it] = (c & 15) << 3;
            vst[it] = *(const f16x8*)(qkv + (seqbase + kc + vkv[it]) * 3 * 2048 + 4096 +
                                      h * 128 + vdb[it]);
        }
#pragma unroll
        for (int it = 0; it < 2; ++it)
#pragma unroll
            for (int i = 0; i < 8; ++i)
                Vt[(vdb[it] + i) * 34 + vkv[it]] = vst[it][i];
        __syncthreads();

        // S^T tiles = mfma(K-frag, Q-frag): lane holds S[q=li][kv = kvt*16 + 4lh + r]
        f32x4 s0 = (f32x4){0.f, 0.f, 0.f, 0.f}, s1 = s0;
#pragma unroll
        for (int c = 0; c < 4; ++c) {
            f16x8 kf0 = *(const f16x8*)(Kl + li * 128 + c * 32 + lh * 8);
            f16x8 kf1 = *(const f16x8*)(Kl + (16 + li) * 128 + c * 32 + lh * 8);
            s0 = __builtin_amdgcn_mfma_f32_16x16x32_f16(kf0, qreg[c], s0, 0, 0, 0);
            s1 = __builtin_amdgcn_mfma_f32_16x16x32_f16(kf1, qreg[c], s1, 0, 0, 0);
        }

        float s[8];
#pragma unroll
        for (int r = 0; r < 4; ++r) { s[r] = s0[r] * SCALE; s[4 + r] = s1[r] * SCALE; }
        float mx = s[0];
#pragma unroll
        for (int i = 1; i < 8; ++i) mx = fmaxf(mx, s[i]);
        mx = fmaxf(mx, __shfl_xor(mx, 16));
        mx = fmaxf(mx, __shfl_xor(mx, 32));
        const float mn = fmaxf(mrun, mx);
        const float alpha = __expf(mrun - mn);
        float p[8], ls = 0.f;
#pragma unroll
        for (int i = 0; i < 8; ++i) { p[i] = __expf(s[i] - mn); ls += p[i]; }
        ls += __shfl_xor(ls, 16);
        ls += __shfl_xor(ls, 32);
        lrun = lrun * alpha + ls;
        mrun = mn;

        float ar[4];
#pragma unroll
        for (int r = 0; r < 4; ++r) ar[r] = __shfl(alpha, ((lane >> 4) << 2) + r);
#pragma unroll
        for (int dt = 0; dt < 8; ++dt)
#pragma unroll
            for (int r = 0; r < 4; ++r) oacc[dt][r] *= ar[r];

        // P as A-operand: slot (lh, j) -> kv = 4lh + (j&3) + 16*(j>>2)
        f16x8 pa;
#pragma unroll
        for (int i = 0; i < 8; ++i) pa[i] = (f16_t)p[i];

#pragma unroll
        for (int dt = 0; dt < 8; ++dt) {
            const int drow = dt * 16 + li;
            f16x2 a0 = *(const f16x2*)(Vt + drow * 34 + 4 * lh);
            f16x2 a1 = *(const f16x2*)(Vt + drow * 34 + 4 * lh + 2);
            f16x2 b0 = *(const f16x2*)(Vt + drow * 34 + 16 + 4 * lh);
            f16x2 b1 = *(const f16x2*)(Vt + drow * 34 + 16 + 4 * lh + 2);
            f16x8 vf = {a0[0], a0[1], a1[0], a1[1], b0[0], b0[1], b1[0], b1[1]};
            oacc[dt] = __builtin_amdgcn_mfma_f32_16x16x32_f16(pa, vf, oacc[dt], 0, 0, 0);
        }
    }

    const float inv = 1.f / lrun;
    float ir[4];
#pragma unroll
    for (int r = 0; r < 4; ++r) ir[r] = __shfl(inv, ((lane >> 4) << 2) + r);
#pragma unroll
    for (int dt = 0; dt < 8; ++dt)
#pragma unroll
        for (int r = 0; r < 4; ++r) {
            const int row = qt * 64 + wave * 16 + 4 * lh + r;
            out[(seqbase + row) * 2048 + h * 128 + dt * 16 + li] =
                (f16_t)(oacc[dt][r] * ir[r]);
        }
}

extern "C" void kernel_launch(void* const* d_in, const int* in_sizes, int n_in,
                              void* d_out, int out_size, void* d_ws, size_t ws_size,
                              hipStream_t stream) {
    const float* x       = (const float*)d_in[0];
    const float* pe      = (const float*)d_in[1];
    const float* w_qkv   = (const float*)d_in[2];
    const float* w_o     = (const float*)d_in[3];
    const float* q_scale = (const float*)d_in[4];
    const float* q_bias  = (const float*)d_in[5];
    const float* k_scale = (const float*)d_in[6];
    const float* k_bias  = (const float*)d_in[7];
    float* out = (float*)d_out;

    char* ws = (char*)d_ws;
    f16_t* x16    = (f16_t*)(ws);                                  // 16.8 MB
    f16_t* wqkvT  = (f16_t*)(ws + 16777216);                       // 25.2 MB [6144][2048]
    f16_t* woT    = (f16_t*)(ws + 41943040);                       // 8.4 MB  [2048][2048]
    f16_t* qkv16  = (f16_t*)(ws + 50331648);                       // 50.3 MB [4096][6144]
    f16_t* attn16 = (f16_t*)(ws + 100663296);                      // 16.8 MB [4096][2048]

    // conversions / transposes
    conv_f16<<<4096, 256, 0, stream>>>(x, x16);                    // 4096*2048 / 8 / 256
    transpose_f16<<<dim3(6144 / 32, 2048 / 32), 256, 0, stream>>>(w_qkv, wqkvT, 2048, 6144);
    transpose_f16<<<dim3(2048 / 32, 2048 / 32), 256, 0, stream>>>(w_o, woT, 2048, 2048);

    // qkv = x @ w_qkv  (M=4096, N=6144, K=2048), f16 out
    gemm_f16<1><<<1536, 256, 0, stream>>>(x16, wqkvT, qkv16, 4096, 6144, 2048, 48);

    // RMSNorm + RoPE on q,k
    rmsrope_f16<<<32768, 256, 0, stream>>>(qkv16, pe, q_scale, q_bias, k_scale, k_bias);

    // attention
    attn_f16<<<1024, 256, 0, stream>>>(qkv16, attn16);

    // out = attn @ w_o  (M=4096, N=2048, K=2048), f32 out
    gemm_f16<0><<<512, 256, 0, stream>>>(attn16, woT, out, 4096, 2048, 2048, 16);
}

// Round 3
// 335.592 us; speedup vs baseline: 8.9552x; 1.1948x over previous
//
#include <hip/hip_runtime.h>
#include <hip/hip_bf16.h>

typedef _Float16 f16_t;
typedef _Float16 f16x2 __attribute__((ext_vector_type(2)));
typedef _Float16 f16x4 __attribute__((ext_vector_type(4)));
typedef _Float16 f16x8 __attribute__((ext_vector_type(8)));
typedef float f32x4 __attribute__((ext_vector_type(4)));

#define GLOAD_LDS16(gp, lp)                                                        \
  __builtin_amdgcn_global_load_lds(                                                \
      (const __attribute__((address_space(1))) void*)(gp),                         \
      (__attribute__((address_space(3))) void*)(lp), 16, 0, 0)

// ---------------- f32 -> f16 elementwise convert (8 elems/thread) ----------------
__global__ __launch_bounds__(256) void conv_f16(const float* __restrict__ in,
                                                f16_t* __restrict__ out)
{
    int i = blockIdx.x * 256 + threadIdx.x;
    float4 a = *(const float4*)&in[(size_t)i * 8];
    float4 b = *(const float4*)&in[(size_t)i * 8 + 4];
    f16x8 o = {(f16_t)a.x, (f16_t)a.y, (f16_t)a.z, (f16_t)a.w,
               (f16_t)b.x, (f16_t)b.y, (f16_t)b.z, (f16_t)b.w};
    *(f16x8*)&out[(size_t)i * 8] = o;
}

// ------------- f32 [R][C] -> f16 transposed [C][R], 32x32 LDS tiles -------------
__global__ __launch_bounds__(256) void transpose_f16(const float* __restrict__ in,
                                                     f16_t* __restrict__ out,
                                                     int R, int C)
{
    __shared__ float t[32][33];
    const int tr = blockIdx.y, tc = blockIdx.x;
    const int r = threadIdx.x >> 3, c4 = (threadIdx.x & 7) * 4;
    float4 v = *(const float4*)&in[(size_t)(tr * 32 + r) * C + tc * 32 + c4];
    t[r][c4 + 0] = v.x; t[r][c4 + 1] = v.y; t[r][c4 + 2] = v.z; t[r][c4 + 3] = v.w;
    __syncthreads();
    f16x4 o = {(f16_t)t[c4 + 0][r], (f16_t)t[c4 + 1][r],
               (f16_t)t[c4 + 2][r], (f16_t)t[c4 + 3][r]};
    *(f16x4*)&out[(size_t)(tc * 32 + r) * R + tr * 32 + c4] = o;
}

// ---------------- f16 MFMA GEMM: C = A[M][K] @ BT[N][K]^T ----------------
template<int F16OUT>
__global__ __launch_bounds__(256) void gemm_f16(const f16_t* __restrict__ A,
                                                const f16_t* __restrict__ BT,
                                                void* __restrict__ Cout,
                                                int M, int N, int K, int gx)
{
    __shared__ f16_t Asl[128 * 32];
    __shared__ f16_t Bsl[128 * 32];
    const int tid = threadIdx.x, lane = tid & 63, wave = tid >> 6;
    const int lh = lane >> 4, li = lane & 15;
    const int wr = wave >> 1, wc = wave & 1;

    const int nwg = gridDim.x;
    const int bid = blockIdx.x;
    const int swz = (bid & 7) * (nwg >> 3) + (bid >> 3);
    const int bx = swz % gx, by = swz / gx;

    const size_t bmK = (size_t)(by * 128) * K;
    const size_t bnK = (size_t)(bx * 128) * K;

    f32x4 acc[4][4];
#pragma unroll
    for (int i = 0; i < 4; ++i)
#pragma unroll
        for (int j = 0; j < 4; ++j) acc[i][j] = (f32x4){0.f, 0.f, 0.f, 0.f};

    for (int k0 = 0; k0 < K; k0 += 32) {
        __syncthreads();
#pragma unroll
        for (int it = 0; it < 2; ++it) {
            const int c = it * 256 + tid;
            const int row = c >> 2, kb = (c & 3) << 3;
            const int ldsoff = (it * 256 + wave * 64) * 16;
            GLOAD_LDS16(A + bmK + (size_t)row * K + k0 + kb, (char*)Asl + ldsoff);
            GLOAD_LDS16(BT + bnK + (size_t)row * K + k0 + kb, (char*)Bsl + ldsoff);
        }
        __syncthreads();
        f16x8 af[4], bf[4];
#pragma unroll
        for (int mi = 0; mi < 4; ++mi)
            af[mi] = *(const f16x8*)(Asl + (wr * 64 + mi * 16 + li) * 32 + lh * 8);
#pragma unroll
        for (int ni = 0; ni < 4; ++ni)
            bf[ni] = *(const f16x8*)(Bsl + (wc * 64 + ni * 16 + li) * 32 + lh * 8);
#pragma unroll
        for (int mi = 0; mi < 4; ++mi)
#pragma unroll
            for (int ni = 0; ni < 4; ++ni)
                acc[mi][ni] = __builtin_amdgcn_mfma_f32_16x16x32_f16(af[mi], bf[ni],
                                                                     acc[mi][ni], 0, 0, 0);
    }

#pragma unroll
    for (int mi = 0; mi < 4; ++mi)
#pragma unroll
        for (int ni = 0; ni < 4; ++ni)
#pragma unroll
            for (int r = 0; r < 4; ++r) {
                const int row = by * 128 + wr * 64 + mi * 16 + lh * 4 + r;
                const int col = bx * 128 + wc * 64 + ni * 16 + li;
                if (F16OUT)
                    ((f16_t*)Cout)[(size_t)row * N + col] = (f16_t)acc[mi][ni][r];
                else
                    ((float*)Cout)[(size_t)row * N + col] = acc[mi][ni][r];
            }
}

// --------- fused RMSNorm + RoPE in-place on f16 qkv[B*S][3][16][128] ---------
__global__ __launch_bounds__(256) void rmsrope_f16(f16_t* __restrict__ qkv,
                                                   const float* __restrict__ pe,
                                                   const float* __restrict__ qs,
                                                   const float* __restrict__ qb,
                                                   const float* __restrict__ ks,
                                                   const float* __restrict__ kb)
{
    const int unit = blockIdx.x * 4 + (threadIdx.x >> 6);
    const int l = threadIdx.x & 63;
    const int bs = unit >> 5, h = (unit >> 1) & 15, comp = unit & 1;
    f16_t* base = qkv + ((size_t)bs * 3 + comp) * 2048 + h * 128;
    const float* sc = comp ? ks : qs;
    const float* bi = comp ? kb : qb;

    f16x2 u = *(const f16x2*)(base + 2 * l);
    float u0 = (float)u[0], u1 = (float)u[1];
    float ss = u0 * u0 + u1 * u1;
#pragma unroll
    for (int o = 32; o; o >>= 1) ss += __shfl_xor(ss, o);
    float inv = rsqrtf(ss * (1.f / 128.f) + 1e-6f);

    float2 scv = *(const float2*)(sc + 2 * l);
    float2 biv = *(const float2*)(bi + 2 * l);
    float a = u0 * inv * scv.x + biv.x;
    float c = u1 * inv * scv.y + biv.y;
    float4 p4 = *(const float4*)(pe + (size_t)bs * 256 + l * 4);
    f16x2 o = {(f16_t)(p4.x * a + p4.y * c), (f16_t)(p4.z * a + p4.w * c)};
    *(f16x2*)(base + 2 * l) = o;
}

// ---------------- flash attention v2: 4 waves x 32 q-rows, KVBLK=64 ----------------
// K in LDS (double-buffered, XOR-swizzled via pre-swizzled global source for
// global_load_lds); V transposed in LDS via f16x4 reg loads + ds_write_b128.
// Swapped QK^T keeps scores in-lane; defer-max skips O-rescale.
__global__ __launch_bounds__(256) void attn_f16(const f16_t* __restrict__ qkv,
                                                f16_t* __restrict__ out)
{
    __shared__ f16_t Kl[2][64 * 128];
    __shared__ f16_t Vt[128 * 72];      // [d][kv], pad 72 (16B-aligned rows)
    const int tid = threadIdx.x, lane = tid & 63, wave = tid >> 6;
    const int lh = lane >> 4, li = lane & 15;
    const int bidx = blockIdx.x;        // qt*64 + (b*16 + h): qt in high bits -> same
    const int bh = bidx & 63;           // (b,h) shares an XCD across its 8 q-tiles
    const int qt = bidx >> 6;
    const int h = bh & 15, b = bh >> 4;
    const size_t seqbase = (size_t)b * 1024;
    const float SCALE = 0.08838834764831845f;  // 1/sqrt(128), folded into Q

    // Q hoist: 2 frags (q = qbase + qf*16 + li), pre-scaled
    const int qbase = qt * 128 + wave * 32;
    f16x8 qreg[2][4];
#pragma unroll
    for (int qf = 0; qf < 2; ++qf) {
        const f16_t* qp = qkv + (seqbase + qbase + qf * 16 + li) * 6144 + h * 128;
#pragma unroll
        for (int c = 0; c < 4; ++c) {
            f16x8 v = *(const f16x8*)(qp + c * 32 + lh * 8);
#pragma unroll
            for (int j = 0; j < 8; ++j) v[j] = (f16_t)((float)v[j] * SCALE);
            qreg[qf][c] = v;
        }
    }

    f32x4 oacc[2][8];
#pragma unroll
    for (int qf = 0; qf < 2; ++qf)
#pragma unroll
        for (int dt = 0; dt < 8; ++dt) oacc[qf][dt] = (f32x4){0.f, 0.f, 0.f, 0.f};
    float mrun[2] = {-1e30f, -1e30f}, lrun[2] = {0.f, 0.f};

    // V staging map: thread -> d0 = (tid&31)*4, kv0 = (tid>>5)*8
    const int vd0 = (tid & 31) * 4;
    const int vk0 = (tid >> 5) * 8;
    f16x4 vreg[8];

    // K staging: 4 its of 256 16B chunks; chunk c: row=c>>4, cc=c&15.
    // Source pre-swizzle cc^(row&7); LDS linear. Reader XORs by (row&7).
#define STAGE_K(t, buf)                                                            \
    do {                                                                           \
        _Pragma("unroll")                                                          \
        for (int it = 0; it < 4; ++it) {                                           \
            const int c_ = it * 256 + tid;                                         \
            const int row_ = c_ >> 4, cc_ = c_ & 15;                               \
            const f16_t* src_ = qkv + (seqbase + (t) * 64 + row_) * 6144 + 2048 +  \
                                h * 128 + ((cc_ ^ (row_ & 7)) << 3);               \
            GLOAD_LDS16(src_, (char*)&Kl[buf][0] + (it * 256 + wave * 64) * 16);   \
        }                                                                          \
    } while (0)

#define LOAD_V(t)                                                                  \
    do {                                                                           \
        _Pragma("unroll")                                                          \
        for (int r_ = 0; r_ < 8; ++r_)                                             \
            vreg[r_] = *(const f16x4*)(qkv + (seqbase + (t) * 64 + vk0 + r_) *     \
                                       6144 + 4096 + h * 128 + vd0);               \
    } while (0)

    STAGE_K(0, 0);
    LOAD_V(0);

    for (int t = 0; t < 16; ++t) {
        const int buf = t & 1;
        __syncthreads();   // (a) K(t) gload drained; prev-iter Vt/Kl reads done

        // write Vt from vreg: per d-row, 8 kv-contiguous halves = ds_write_b128
#pragma unroll
        for (int dd = 0; dd < 4; ++dd) {
            f16x8 w;
#pragma unroll
            for (int r = 0; r < 8; ++r) w[r] = vreg[r][dd];
            *(f16x8*)&Vt[(vd0 + dd) * 72 + vk0] = w;
        }
        __syncthreads();   // (b) Vt + Kl[buf] visible

        // prefetch next tile AFTER barrier (stays in flight through compute)
        if (t < 15) {
            STAGE_K(t + 1, buf ^ 1);
            LOAD_V(t + 1);
        }

        // QK^T: s[qf][kvt*4+r] = S[q = qbase+qf*16+li][kv = t*64 + kvt*16 + 4lh + r]
        float s[2][16];
#pragma unroll
        for (int kvt = 0; kvt < 4; ++kvt) {
            f32x4 a0 = (f32x4){0.f, 0.f, 0.f, 0.f}, a1 = a0;
#pragma unroll
            for (int c = 0; c < 4; ++c) {
                const int kvrow = kvt * 16 + li;
                f16x8 kf = *(const f16x8*)&Kl[buf][kvrow * 128 +
                                                   (((c * 4 + lh) ^ (li & 7)) << 3)];
                a0 = __builtin_amdgcn_mfma_f32_16x16x32_f16(kf, qreg[0][c], a0, 0, 0, 0);
                a1 = __builtin_amdgcn_mfma_f32_16x16x32_f16(kf, qreg[1][c], a1, 0, 0, 0);
            }
#pragma unroll
            for (int r = 0; r < 4; ++r) { s[0][kvt * 4 + r] = a0[r]; s[1][kvt * 4 + r] = a1[r]; }
        }

        // online softmax with defer-max (THR=8)
        float pmax[2];
#pragma unroll
        for (int qf = 0; qf < 2; ++qf) {
            float mx = s[qf][0];
#pragma unroll
            for (int i = 1; i < 16; ++i) mx = fmaxf(mx, s[qf][i]);
            mx = fmaxf(mx, __shfl_xor(mx, 16));
            mx = fmaxf(mx, __shfl_xor(mx, 32));
            pmax[qf] = mx;
        }
        const bool defer = __all((pmax[0] - mrun[0] <= 8.f) && (pmax[1] - mrun[1] <= 8.f));
        if (!defer) {
#pragma unroll
            for (int qf = 0; qf < 2; ++qf) {
                const float mn = fmaxf(mrun[qf], pmax[qf]);
                const float alpha = __expf(mrun[qf] - mn);
                lrun[qf] *= alpha;
                mrun[qf] = mn;
                float ar[4];
#pragma unroll
                for (int r = 0; r < 4; ++r) ar[r] = __shfl(alpha, 4 * lh + r);
#pragma unroll
                for (int dt = 0; dt < 8; ++dt)
#pragma unroll
                    for (int r = 0; r < 4; ++r) oacc[qf][dt][r] *= ar[r];
            }
        }

        f16x8 pa[2][2];
#pragma unroll
        for (int qf = 0; qf < 2; ++qf) {
            float ls = 0.f;
            float p[16];
#pragma unroll
            for (int i = 0; i < 16; ++i) { p[i] = __expf(s[qf][i] - mrun[qf]); ls += p[i]; }
            ls += __shfl_xor(ls, 16);
            ls += __shfl_xor(ls, 32);
            lrun[qf] += ls;
            // pa slot j (half hf): kv = 32*hf + 16*(j>>2) + 4lh + (j&3)
#pragma unroll
            for (int hf = 0; hf < 2; ++hf)
#pragma unroll
                for (int j = 0; j < 8; ++j)
                    pa[qf][hf][j] = (f16_t)p[(2 * hf + (j >> 2)) * 4 + (j & 3)];
        }

        // PV: vf slot j matches pa's kv map
#pragma unroll
        for (int dt = 0; dt < 8; ++dt) {
            const int drow = dt * 16 + li;
            f16x4 v0 = *(const f16x4*)&Vt[drow * 72 + 4 * lh];
            f16x4 v1 = *(const f16x4*)&Vt[drow * 72 + 16 + 4 * lh];
            f16x4 v2 = *(const f16x4*)&Vt[drow * 72 + 32 + 4 * lh];
            f16x4 v3 = *(const f16x4*)&Vt[drow * 72 + 48 + 4 * lh];
            f16x8 vf0 = {v0[0], v0[1], v0[2], v0[3], v1[0], v1[1], v1[2], v1[3]};
            f16x8 vf1 = {v2[0], v2[1], v2[2], v2[3], v3[0], v3[1], v3[2], v3[3]};
#pragma unroll
            for (int qf = 0; qf < 2; ++qf) {
                oacc[qf][dt] = __builtin_amdgcn_mfma_f32_16x16x32_f16(pa[qf][0], vf0,
                                                                      oacc[qf][dt], 0, 0, 0);
                oacc[qf][dt] = __builtin_amdgcn_mfma_f32_16x16x32_f16(pa[qf][1], vf1,
                                                                      oacc[qf][dt], 0, 0, 0);
            }
        }
    }

#pragma unroll
    for (int qf = 0; qf < 2; ++qf) {
        const float inv = 1.f / lrun[qf];
        float ir[4];
#pragma unroll
        for (int r = 0; r < 4; ++r) ir[r] = __shfl(inv, 4 * lh + r);
#pragma unroll
        for (int dt = 0; dt < 8; ++dt)
#pragma unroll
            for (int r = 0; r < 4; ++r) {
                const int row = qbase + qf * 16 + 4 * lh + r;
                out[(seqbase + row) * 2048 + h * 128 + dt * 16 + li] =
                    (f16_t)(oacc[qf][dt][r] * ir[r]);
            }
    }
#undef STAGE_K
#undef LOAD_V
}

extern "C" void kernel_launch(void* const* d_in, const int* in_sizes, int n_in,
                              void* d_out, int out_size, void* d_ws, size_t ws_size,
                              hipStream_t stream) {
    const float* x       = (const float*)d_in[0];
    const float* pe      = (const float*)d_in[1];
    const float* w_qkv   = (const float*)d_in[2];
    const float* w_o     = (const float*)d_in[3];
    const float* q_scale = (const float*)d_in[4];
    const float* q_bias  = (const float*)d_in[5];
    const float* k_scale = (const float*)d_in[6];
    const float* k_bias  = (const float*)d_in[7];
    float* out = (float*)d_out;

    char* ws = (char*)d_ws;
    f16_t* x16    = (f16_t*)(ws);
    f16_t* wqkvT  = (f16_t*)(ws + 16777216);
    f16_t* woT    = (f16_t*)(ws + 41943040);
    f16_t* qkv16  = (f16_t*)(ws + 50331648);
    f16_t* attn16 = (f16_t*)(ws + 100663296);

    conv_f16<<<4096, 256, 0, stream>>>(x, x16);
    transpose_f16<<<dim3(6144 / 32, 2048 / 32), 256, 0, stream>>>(w_qkv, wqkvT, 2048, 6144);
    transpose_f16<<<dim3(2048 / 32, 2048 / 32), 256, 0, stream>>>(w_o, woT, 2048, 2048);

    gemm_f16<1><<<1536, 256, 0, stream>>>(x16, wqkvT, qkv16, 4096, 6144, 2048, 48);

    rmsrope_f16<<<32768, 256, 0, stream>>>(qkv16, pe, q_scale, q_bias, k_scale, k_bias);

    attn_f16<<<512, 256, 0, stream>>>(qkv16, attn16);

    gemm_f16<0><<<512, 256, 0, stream>>>(attn16, woT, out, 4096, 2048, 2048, 16);
}

// Round 4
// 327.449 us; speedup vs baseline: 9.1779x; 1.0249x over previous
//
#include <hip/hip_runtime.h>
#include <hip/hip_bf16.h>

typedef _Float16 f16_t;
typedef _Float16 f16x2 __attribute__((ext_vector_type(2)));
typedef _Float16 f16x4 __attribute__((ext_vector_type(4)));
typedef _Float16 f16x8 __attribute__((ext_vector_type(8)));
typedef float f32x4 __attribute__((ext_vector_type(4)));

#define GLOAD_LDS16(gp, lp)                                                        \
  __builtin_amdgcn_global_load_lds(                                                \
      (const __attribute__((address_space(1))) void*)(gp),                         \
      (__attribute__((address_space(3))) void*)(lp), 16, 0, 0)

// ---------------- f32 -> f16 elementwise convert (8 elems/thread) ----------------
__global__ __launch_bounds__(256) void conv_f16(const float* __restrict__ in,
                                                f16_t* __restrict__ out)
{
    int i = blockIdx.x * 256 + threadIdx.x;
    float4 a = *(const float4*)&in[(size_t)i * 8];
    float4 b = *(const float4*)&in[(size_t)i * 8 + 4];
    f16x8 o = {(f16_t)a.x, (f16_t)a.y, (f16_t)a.z, (f16_t)a.w,
               (f16_t)b.x, (f16_t)b.y, (f16_t)b.z, (f16_t)b.w};
    *(f16x8*)&out[(size_t)i * 8] = o;
}

// ------------- f32 [R][C] -> f16 transposed [C][R], 32x32 LDS tiles -------------
__global__ __launch_bounds__(256) void transpose_f16(const float* __restrict__ in,
                                                     f16_t* __restrict__ out,
                                                     int R, int C)
{
    __shared__ float t[32][33];
    const int tr = blockIdx.y, tc = blockIdx.x;
    const int r = threadIdx.x >> 3, c4 = (threadIdx.x & 7) * 4;
    float4 v = *(const float4*)&in[(size_t)(tr * 32 + r) * C + tc * 32 + c4];
    t[r][c4 + 0] = v.x; t[r][c4 + 1] = v.y; t[r][c4 + 2] = v.z; t[r][c4 + 3] = v.w;
    __syncthreads();
    f16x4 o = {(f16_t)t[c4 + 0][r], (f16_t)t[c4 + 1][r],
               (f16_t)t[c4 + 2][r], (f16_t)t[c4 + 3][r]};
    *(f16x4*)&out[(size_t)(tc * 32 + r) * R + tr * 32 + c4] = o;
}

// ------------- f16 MFMA GEMM v2: C = A[M][K] @ BT[N][K]^T -------------
// 128x128 tile, BK=32, 4 waves (2x2, wave tile 64x64). 4 LDS buffers (64 KB),
// depth-3 pipeline with counted vmcnt(8); T2 16B-unit XOR swizzle (linear LDS,
// pre-swizzled global source); raw s_barrier (no vmcnt drain); setprio on MFMA.
template<int F16OUT>
__global__ __launch_bounds__(256, 2) void gemm_v2(const f16_t* __restrict__ A,
                                                  const f16_t* __restrict__ BT,
                                                  void* __restrict__ Cout,
                                                  int M, int N, int K, int gx)
{
    __shared__ f16_t As[4][128 * 32];
    __shared__ f16_t Bs[4][128 * 32];
    const int tid = threadIdx.x, lane = tid & 63, wave = tid >> 6;
    const int lh = lane >> 4, li = lane & 15;
    const int wr = wave >> 1, wc = wave & 1;

    const int nwg = gridDim.x;
    const int bid = blockIdx.x;
    const int swz = (bid & 7) * (nwg >> 3) + (bid >> 3);
    const int bx = swz % gx, by = swz / gx;

    const size_t bmK = (size_t)(by * 128) * K;
    const size_t bnK = (size_t)(bx * 128) * K;
    const int NT = K >> 5;

    f32x4 acc[4][4];
#pragma unroll
    for (int i = 0; i < 4; ++i)
#pragma unroll
        for (int j = 0; j < 4; ++j) acc[i][j] = (f32x4){0.f, 0.f, 0.f, 0.f};

    // stage K-tile t into buffer t&3. chunk c (0..511): row=c>>2, lds unit u=c&3,
    // global unit gu = u ^ ((row>>1)&3). LDS linear; 2 gloads per thread per matrix.
#define STAGE(t)                                                                   \
    do {                                                                           \
        const int buf_ = (t) & 3;                                                  \
        const size_t kof_ = (size_t)(t) << 5;                                      \
        _Pragma("unroll")                                                          \
        for (int i_ = 0; i_ < 2; ++i_) {                                           \
            const int c_ = i_ * 256 + tid;                                         \
            const int row_ = c_ >> 2;                                              \
            const int gu_ = (c_ & 3) ^ ((row_ >> 1) & 3);                          \
            const int ldsoff_ = (i_ * 256 + wave * 64) * 16;                       \
            GLOAD_LDS16(A + bmK + (size_t)row_ * K + kof_ + gu_ * 8,               \
                        (char*)&As[buf_][0] + ldsoff_);                            \
            GLOAD_LDS16(BT + bnK + (size_t)row_ * K + kof_ + gu_ * 8,              \
                        (char*)&Bs[buf_][0] + ldsoff_);                            \
        }                                                                          \
    } while (0)

    STAGE(0);
    STAGE(1);
    STAGE(2);

    // read swizzle: s = (li>>1)&3 (row bits 1-2), unit = lh ^ s
    const int runit = (lh ^ ((li >> 1) & 3)) << 3;

    for (int t = 0; t < NT; ++t) {
        if (t + 2 < NT)      asm volatile("s_waitcnt vmcnt(8)" ::: "memory");
        else if (t + 1 < NT) asm volatile("s_waitcnt vmcnt(4)" ::: "memory");
        else                 asm volatile("s_waitcnt vmcnt(0)" ::: "memory");
        __builtin_amdgcn_s_barrier();

        if (t + 3 < NT) STAGE(t + 3);

        const int buf = t & 3;
        f16x8 af[4], bf[4];
#pragma unroll
        for (int mf = 0; mf < 4; ++mf)
            af[mf] = *(const f16x8*)&As[buf][(wr * 64 + mf * 16 + li) * 32 + runit];
#pragma unroll
        for (int nf = 0; nf < 4; ++nf)
            bf[nf] = *(const f16x8*)&Bs[buf][(wc * 64 + nf * 16 + li) * 32 + runit];

        __builtin_amdgcn_s_setprio(1);
#pragma unroll
        for (int mf = 0; mf < 4; ++mf)
#pragma unroll
            for (int nf = 0; nf < 4; ++nf)
                acc[mf][nf] = __builtin_amdgcn_mfma_f32_16x16x32_f16(af[mf], bf[nf],
                                                                     acc[mf][nf], 0, 0, 0);
        __builtin_amdgcn_s_setprio(0);
        __builtin_amdgcn_sched_barrier(0);
    }
#undef STAGE

    // C/D layout: col = lane&15, row = (lane>>4)*4 + reg
#pragma unroll
    for (int mf = 0; mf < 4; ++mf)
#pragma unroll
        for (int nf = 0; nf < 4; ++nf)
#pragma unroll
            for (int r = 0; r < 4; ++r) {
                const int row = by * 128 + wr * 64 + mf * 16 + lh * 4 + r;
                const int col = bx * 128 + wc * 64 + nf * 16 + li;
                if (F16OUT)
                    ((f16_t*)Cout)[(size_t)row * N + col] = (f16_t)acc[mf][nf][r];
                else
                    ((float*)Cout)[(size_t)row * N + col] = acc[mf][nf][r];
            }
}

// --------- fused RMSNorm + RoPE in-place on f16 qkv[B*S][3][16][128] ---------
__global__ __launch_bounds__(256) void rmsrope_f16(f16_t* __restrict__ qkv,
                                                   const float* __restrict__ pe,
                                                   const float* __restrict__ qs,
                                                   const float* __restrict__ qb,
                                                   const float* __restrict__ ks,
                                                   const float* __restrict__ kb)
{
    const int unit = blockIdx.x * 4 + (threadIdx.x >> 6);
    const int l = threadIdx.x & 63;
    const int bs = unit >> 5, h = (unit >> 1) & 15, comp = unit & 1;
    f16_t* base = qkv + ((size_t)bs * 3 + comp) * 2048 + h * 128;
    const float* sc = comp ? ks : qs;
    const float* bi = comp ? kb : qb;

    f16x2 u = *(const f16x2*)(base + 2 * l);
    float u0 = (float)u[0], u1 = (float)u[1];
    float ss = u0 * u0 + u1 * u1;
#pragma unroll
    for (int o = 32; o; o >>= 1) ss += __shfl_xor(ss, o);
    float inv = rsqrtf(ss * (1.f / 128.f) + 1e-6f);

    float2 scv = *(const float2*)(sc + 2 * l);
    float2 biv = *(const float2*)(bi + 2 * l);
    float a = u0 * inv * scv.x + biv.x;
    float c = u1 * inv * scv.y + biv.y;
    float4 p4 = *(const float4*)(pe + (size_t)bs * 256 + l * 4);
    f16x2 o = {(f16_t)(p4.x * a + p4.y * c), (f16_t)(p4.z * a + p4.w * c)};
    *(f16x2*)(base + 2 * l) = o;
}

// ---------------- flash attention: 4 waves x 32 q-rows, KVBLK=64 ----------------
__global__ __launch_bounds__(256) void attn_f16(const f16_t* __restrict__ qkv,
                                                f16_t* __restrict__ out)
{
    __shared__ f16_t Kl[2][64 * 128];
    __shared__ f16_t Vt[128 * 72];
    const int tid = threadIdx.x, lane = tid & 63, wave = tid >> 6;
    const int lh = lane >> 4, li = lane & 15;
    const int bidx = blockIdx.x;
    const int bh = bidx & 63;
    const int qt = bidx >> 6;
    const int h = bh & 15, b = bh >> 4;
    const size_t seqbase = (size_t)b * 1024;
    const float SCALE = 0.08838834764831845f;

    const int qbase = qt * 128 + wave * 32;
    f16x8 qreg[2][4];
#pragma unroll
    for (int qf = 0; qf < 2; ++qf) {
        const f16_t* qp = qkv + (seqbase + qbase + qf * 16 + li) * 6144 + h * 128;
#pragma unroll
        for (int c = 0; c < 4; ++c) {
            f16x8 v = *(const f16x8*)(qp + c * 32 + lh * 8);
#pragma unroll
            for (int j = 0; j < 8; ++j) v[j] = (f16_t)((float)v[j] * SCALE);
            qreg[qf][c] = v;
        }
    }

    f32x4 oacc[2][8];
#pragma unroll
    for (int qf = 0; qf < 2; ++qf)
#pragma unroll
        for (int dt = 0; dt < 8; ++dt) oacc[qf][dt] = (f32x4){0.f, 0.f, 0.f, 0.f};
    float mrun[2] = {-1e30f, -1e30f}, lrun[2] = {0.f, 0.f};

    const int vd0 = (tid & 31) * 4;
    const int vk0 = (tid >> 5) * 8;
    f16x4 vreg[8];

#define STAGE_K(t, buf)                                                            \
    do {                                                                           \
        _Pragma("unroll")                                                          \
        for (int it = 0; it < 4; ++it) {                                           \
            const int c_ = it * 256 + tid;                                         \
            const int row_ = c_ >> 4, cc_ = c_ & 15;                               \
            const f16_t* src_ = qkv + (seqbase + (t) * 64 + row_) * 6144 + 2048 +  \
                                h * 128 + ((cc_ ^ (row_ & 7)) << 3);               \
            GLOAD_LDS16(src_, (char*)&Kl[buf][0] + (it * 256 + wave * 64) * 16);   \
        }                                                                          \
    } while (0)

#define LOAD_V(t)                                                                  \
    do {                                                                           \
        _Pragma("unroll")                                                          \
        for (int r_ = 0; r_ < 8; ++r_)                                             \
            vreg[r_] = *(const f16x4*)(qkv + (seqbase + (t) * 64 + vk0 + r_) *     \
                                       6144 + 4096 + h * 128 + vd0);               \
    } while (0)

    STAGE_K(0, 0);
    LOAD_V(0);

    for (int t = 0; t < 16; ++t) {
        const int buf = t & 1;
        __syncthreads();

#pragma unroll
        for (int dd = 0; dd < 4; ++dd) {
            f16x8 w;
#pragma unroll
            for (int r = 0; r < 8; ++r) w[r] = vreg[r][dd];
            *(f16x8*)&Vt[(vd0 + dd) * 72 + vk0] = w;
        }
        __syncthreads();

        if (t < 15) {
            STAGE_K(t + 1, buf ^ 1);
            LOAD_V(t + 1);
        }

        float s[2][16];
#pragma unroll
        for (int kvt = 0; kvt < 4; ++kvt) {
            f32x4 a0 = (f32x4){0.f, 0.f, 0.f, 0.f}, a1 = a0;
#pragma unroll
            for (int c = 0; c < 4; ++c) {
                const int kvrow = kvt * 16 + li;
                f16x8 kf = *(const f16x8*)&Kl[buf][kvrow * 128 +
                                                   (((c * 4 + lh) ^ (li & 7)) << 3)];
                a0 = __builtin_amdgcn_mfma_f32_16x16x32_f16(kf, qreg[0][c], a0, 0, 0, 0);
                a1 = __builtin_amdgcn_mfma_f32_16x16x32_f16(kf, qreg[1][c], a1, 0, 0, 0);
            }
#pragma unroll
            for (int r = 0; r < 4; ++r) { s[0][kvt * 4 + r] = a0[r]; s[1][kvt * 4 + r] = a1[r]; }
        }

        float pmax[2];
#pragma unroll
        for (int qf = 0; qf < 2; ++qf) {
            float mx = s[qf][0];
#pragma unroll
            for (int i = 1; i < 16; ++i) mx = fmaxf(mx, s[qf][i]);
            mx = fmaxf(mx, __shfl_xor(mx, 16));
            mx = fmaxf(mx, __shfl_xor(mx, 32));
            pmax[qf] = mx;
        }
        const bool defer = __all((pmax[0] - mrun[0] <= 8.f) && (pmax[1] - mrun[1] <= 8.f));
        if (!defer) {
#pragma unroll
            for (int qf = 0; qf < 2; ++qf) {
                const float mn = fmaxf(mrun[qf], pmax[qf]);
                const float alpha = __expf(mrun[qf] - mn);
                lrun[qf] *= alpha;
                mrun[qf] = mn;
                float ar[4];
#pragma unroll
                for (int r = 0; r < 4; ++r) ar[r] = __shfl(alpha, 4 * lh + r);
#pragma unroll
                for (int dt = 0; dt < 8; ++dt)
#pragma unroll
                    for (int r = 0; r < 4; ++r) oacc[qf][dt][r] *= ar[r];
            }
        }

        f16x8 pa[2][2];
#pragma unroll
        for (int qf = 0; qf < 2; ++qf) {
            float ls = 0.f;
            float p[16];
#pragma unroll
            for (int i = 0; i < 16; ++i) { p[i] = __expf(s[qf][i] - mrun[qf]); ls += p[i]; }
            ls += __shfl_xor(ls, 16);
            ls += __shfl_xor(ls, 32);
            lrun[qf] += ls;
#pragma unroll
            for (int hf = 0; hf < 2; ++hf)
#pragma unroll
                for (int j = 0; j < 8; ++j)
                    pa[qf][hf][j] = (f16_t)p[(2 * hf + (j >> 2)) * 4 + (j & 3)];
        }

#pragma unroll
        for (int dt = 0; dt < 8; ++dt) {
            const int drow = dt * 16 + li;
            f16x4 v0 = *(const f16x4*)&Vt[drow * 72 + 4 * lh];
            f16x4 v1 = *(const f16x4*)&Vt[drow * 72 + 16 + 4 * lh];
            f16x4 v2 = *(const f16x4*)&Vt[drow * 72 + 32 + 4 * lh];
            f16x4 v3 = *(const f16x4*)&Vt[drow * 72 + 48 + 4 * lh];
            f16x8 vf0 = {v0[0], v0[1], v0[2], v0[3], v1[0], v1[1], v1[2], v1[3]};
            f16x8 vf1 = {v2[0], v2[1], v2[2], v2[3], v3[0], v3[1], v3[2], v3[3]};
#pragma unroll
            for (int qf = 0; qf < 2; ++qf) {
                oacc[qf][dt] = __builtin_amdgcn_mfma_f32_16x16x32_f16(pa[qf][0], vf0,
                                                                      oacc[qf][dt], 0, 0, 0);
                oacc[qf][dt] = __builtin_amdgcn_mfma_f32_16x16x32_f16(pa[qf][1], vf1,
                                                                      oacc[qf][dt], 0, 0, 0);
            }
        }
    }

#pragma unroll
    for (int qf = 0; qf < 2; ++qf) {
        const float inv = 1.f / lrun[qf];
        float ir[4];
#pragma unroll
        for (int r = 0; r < 4; ++r) ir[r] = __shfl(inv, 4 * lh + r);
#pragma unroll
        for (int dt = 0; dt < 8; ++dt)
#pragma unroll
            for (int r = 0; r < 4; ++r) {
                const int row = qbase + qf * 16 + 4 * lh + r;
                out[(seqbase + row) * 2048 + h * 128 + dt * 16 + li] =
                    (f16_t)(oacc[qf][dt][r] * ir[r]);
            }
    }
#undef STAGE_K
#undef LOAD_V
}

extern "C" void kernel_launch(void* const* d_in, const int* in_sizes, int n_in,
                              void* d_out, int out_size, void* d_ws, size_t ws_size,
                              hipStream_t stream) {
    const float* x       = (const float*)d_in[0];
    const float* pe      = (const float*)d_in[1];
    const float* w_qkv   = (const float*)d_in[2];
    const float* w_o     = (const float*)d_in[3];
    const float* q_scale = (const float*)d_in[4];
    const float* q_bias  = (const float*)d_in[5];
    const float* k_scale = (const float*)d_in[6];
    const float* k_bias  = (const float*)d_in[7];
    float* out = (float*)d_out;

    char* ws = (char*)d_ws;
    f16_t* x16    = (f16_t*)(ws);
    f16_t* wqkvT  = (f16_t*)(ws + 16777216);
    f16_t* woT    = (f16_t*)(ws + 41943040);
    f16_t* qkv16  = (f16_t*)(ws + 50331648);
    f16_t* attn16 = (f16_t*)(ws + 100663296);

    conv_f16<<<4096, 256, 0, stream>>>(x, x16);
    transpose_f16<<<dim3(6144 / 32, 2048 / 32), 256, 0, stream>>>(w_qkv, wqkvT, 2048, 6144);
    transpose_f16<<<dim3(2048 / 32, 2048 / 32), 256, 0, stream>>>(w_o, woT, 2048, 2048);

    gemm_v2<1><<<1536, 256, 0, stream>>>(x16, wqkvT, qkv16, 4096, 6144, 2048, 48);

    rmsrope_f16<<<32768, 256, 0, stream>>>(qkv16, pe, q_scale, q_bias, k_scale, k_bias);

    attn_f16<<<512, 256, 0, stream>>>(qkv16, attn16);

    gemm_v2<0><<<512, 256, 0, stream>>>(attn16, woT, out, 4096, 2048, 2048, 16);
}

// Round 5
// 308.971 us; speedup vs baseline: 9.7268x; 1.0598x over previous
//
#include <hip/hip_runtime.h>
#include <hip/hip_bf16.h>

typedef _Float16 f16_t;
typedef _Float16 f16x2 __attribute__((ext_vector_type(2)));
typedef _Float16 f16x4 __attribute__((ext_vector_type(4)));
typedef _Float16 f16x8 __attribute__((ext_vector_type(8)));
typedef float f32x4 __attribute__((ext_vector_type(4)));

#define GLOAD_LDS16(gp, lp)                                                        \
  __builtin_amdgcn_global_load_lds(                                                \
      (const __attribute__((address_space(1))) void*)(gp),                         \
      (__attribute__((address_space(3))) void*)(lp), 16, 0, 0)

template<int N> __device__ __forceinline__ void vmwait() {
    if constexpr (N >= 12)     asm volatile("s_waitcnt vmcnt(12)" ::: "memory");
    else if constexpr (N == 9) asm volatile("s_waitcnt vmcnt(9)" ::: "memory");
    else if constexpr (N == 8) asm volatile("s_waitcnt vmcnt(8)" ::: "memory");
    else if constexpr (N == 6) asm volatile("s_waitcnt vmcnt(6)" ::: "memory");
    else if constexpr (N == 4) asm volatile("s_waitcnt vmcnt(4)" ::: "memory");
    else if constexpr (N == 3) asm volatile("s_waitcnt vmcnt(3)" ::: "memory");
    else                       asm volatile("s_waitcnt vmcnt(0)" ::: "memory");
}

// ---------------- f32 -> f16 elementwise convert (8 elems/thread) ----------------
__global__ __launch_bounds__(256) void conv_f16(const float* __restrict__ in,
                                                f16_t* __restrict__ out)
{
    int i = blockIdx.x * 256 + threadIdx.x;
    float4 a = *(const float4*)&in[(size_t)i * 8];
    float4 b = *(const float4*)&in[(size_t)i * 8 + 4];
    f16x8 o = {(f16_t)a.x, (f16_t)a.y, (f16_t)a.z, (f16_t)a.w,
               (f16_t)b.x, (f16_t)b.y, (f16_t)b.z, (f16_t)b.w};
    *(f16x8*)&out[(size_t)i * 8] = o;
}

// ------------- f32 [R][C] -> f16 transposed [C][R], 32x32 LDS tiles -------------
__global__ __launch_bounds__(256) void transpose_f16(const float* __restrict__ in,
                                                     f16_t* __restrict__ out,
                                                     int R, int C)
{
    __shared__ float t[32][33];
    const int tr = blockIdx.y, tc = blockIdx.x;
    const int r = threadIdx.x >> 3, c4 = (threadIdx.x & 7) * 4;
    float4 v = *(const float4*)&in[(size_t)(tr * 32 + r) * C + tc * 32 + c4];
    t[r][c4 + 0] = v.x; t[r][c4 + 1] = v.y; t[r][c4 + 2] = v.z; t[r][c4 + 3] = v.w;
    __syncthreads();
    f16x4 o = {(f16_t)t[c4 + 0][r], (f16_t)t[c4 + 1][r],
               (f16_t)t[c4 + 2][r], (f16_t)t[c4 + 3][r]};
    *(f16x4*)&out[(size_t)(tc * 32 + r) * R + tr * 32 + c4] = o;
}

// ------------- f16 MFMA GEMM v3: C = A[M][K] @ BT[N][K]^T -------------
// BM=256, BK=32, 512 threads (8 waves WMC x WNC). 4 LDS buffers (dynamic),
// depth-3 prefetch with counted vmcnt (never 0 in steady state), 2 compute
// phases per K-tile (A-frags split in halves, B-frags reused), T2 XOR swizzle
// (linear LDS dest, pre-swizzled global source), setprio around MFMA clusters.
template<int BN, int WMC, int WNC, int F16OUT>
__global__ __launch_bounds__(512, 2) void gemm_v3(const f16_t* __restrict__ A,
                                                  const f16_t* __restrict__ BT,
                                                  void* __restrict__ Cout,
                                                  int M, int N, int K, int gx)
{
    extern __shared__ char smem[];          // [4][16KB] A | [4][BN*64B] B
    constexpr int WMT = 256 / WMC, WNT = BN / WNC;
    constexpr int MF = WMT / 16, NF = WNT / 16, MFH = MF / 2;
    constexpr int BNL = BN / 128;           // B gloads per thread per tile
    constexpr int L = 2 + BNL;              // gloads per thread per tile

    const int tid = threadIdx.x, lane = tid & 63, wave = tid >> 6;
    const int lh = lane >> 4, li = lane & 15;
    const int wr = wave / WNC, wc = wave % WNC;

    const int nwg = gridDim.x, bid = blockIdx.x;
    const int swz = (bid & 7) * (nwg >> 3) + (bid >> 3);
    const int bx = swz % gx, by = swz / gx;

    const size_t bmK = (size_t)(by * 256) * K;
    const size_t bnK = (size_t)(bx * BN) * K;
    const int NT = K >> 5;

    f32x4 acc[MF][NF];
#pragma unroll
    for (int i = 0; i < MF; ++i)
#pragma unroll
        for (int j = 0; j < NF; ++j) acc[i][j] = (f32x4){0.f, 0.f, 0.f, 0.f};

    // stage K-tile t into buffer t&3; chunk c: row=c>>2, lds unit u=c&3,
    // global unit gu = u ^ ((row>>1)&3); LDS linear (wave-uniform base + lane*16).
#define STAGE(t)                                                                   \
    do {                                                                           \
        const int buf_ = (t) & 3;                                                  \
        const int kof_ = (t) << 5;                                                 \
        char* Ab_ = smem + buf_ * 16384;                                           \
        char* Bb_ = smem + 65536 + buf_ * (BN * 64);                               \
        _Pragma("unroll")                                                          \
        for (int i_ = 0; i_ < 2; ++i_) {                                           \
            const int c_ = i_ * 512 + tid;                                         \
            const int row_ = c_ >> 2;                                              \
            const int gu_ = (c_ & 3) ^ ((row_ >> 1) & 3);                          \
            GLOAD_LDS16(A + bmK + (size_t)row_ * K + kof_ + gu_ * 8,               \
                        Ab_ + (i_ * 512 + wave * 64) * 16);                        \
        }                                                                          \
        _Pragma("unroll")                                                          \
        for (int i_ = 0; i_ < BNL; ++i_) {                                         \
            const int c_ = i_ * 512 + tid;                                         \
            const int row_ = c_ >> 2;                                              \
            const int gu_ = (c_ & 3) ^ ((row_ >> 1) & 3);                          \
            GLOAD_LDS16(BT + bnK + (size_t)row_ * K + kof_ + gu_ * 8,              \
                        Bb_ + (i_ * 512 + wave * 64) * 16);                        \
        }                                                                          \
    } while (0)

    STAGE(0); STAGE(1); STAGE(2); STAGE(3);

    const int runit = (lh ^ ((li >> 1) & 3)) << 3;   // swizzled 8-f16 unit offset

    for (int t = 0; t < NT; ++t) {
        if (t + 3 < NT)      vmwait<3 * L>();
        else if (t + 2 < NT) vmwait<2 * L>();
        else if (t + 1 < NT) vmwait<L>();
        else                 vmwait<0>();
        __builtin_amdgcn_s_barrier();
        __builtin_amdgcn_sched_barrier(0);

        const f16_t* Ab = (const f16_t*)(smem + (t & 3) * 16384);
        const f16_t* Bb = (const f16_t*)(smem + 65536 + (t & 3) * (BN * 64));

        f16x8 af[MFH], bf[NF];
        // ---- phase 0: A-frags half 0 + all B-frags ----
#pragma unroll
        for (int j = 0; j < MFH; ++j)
            af[j] = *(const f16x8*)(Ab + (wr * WMT + j * 16 + li) * 32 + runit);
#pragma unroll
        for (int nf = 0; nf < NF; ++nf)
            bf[nf] = *(const f16x8*)(Bb + (wc * WNT + nf * 16 + li) * 32 + runit);
        __builtin_amdgcn_s_setprio(1);
#pragma unroll
        for (int j = 0; j < MFH; ++j)
#pragma unroll
            for (int nf = 0; nf < NF; ++nf)
                acc[j][nf] = __builtin_amdgcn_mfma_f32_16x16x32_f16(af[j], bf[nf],
                                                                    acc[j][nf], 0, 0, 0);
        __builtin_amdgcn_s_setprio(0);
        __builtin_amdgcn_sched_barrier(0);
        // ---- phase 1: A-frags half 1, reuse B-frags ----
#pragma unroll
        for (int j = 0; j < MFH; ++j)
            af[j] = *(const f16x8*)(Ab + (wr * WMT + (MFH + j) * 16 + li) * 32 + runit);
        __builtin_amdgcn_s_setprio(1);
#pragma unroll
        for (int j = 0; j < MFH; ++j)
#pragma unroll
            for (int nf = 0; nf < NF; ++nf)
                acc[MFH + j][nf] = __builtin_amdgcn_mfma_f32_16x16x32_f16(af[j], bf[nf],
                                                                          acc[MFH + j][nf],
                                                                          0, 0, 0);
        __builtin_amdgcn_s_setprio(0);
        __builtin_amdgcn_sched_barrier(0);

        __builtin_amdgcn_s_barrier();      // all waves done reading buf t&3
        if (t + 4 < NT) STAGE(t + 4);      // refill freed buffer
        __builtin_amdgcn_sched_barrier(0);
    }
#undef STAGE

    // C/D layout: col = lane&15, row = (lane>>4)*4 + reg
#pragma unroll
    for (int mf = 0; mf < MF; ++mf)
#pragma unroll
        for (int nf = 0; nf < NF; ++nf)
#pragma unroll
            for (int r = 0; r < 4; ++r) {
                const int row = by * 256 + wr * WMT + mf * 16 + lh * 4 + r;
                const int col = bx * BN + wc * WNT + nf * 16 + li;
                if (F16OUT)
                    ((f16_t*)Cout)[(size_t)row * N + col] = (f16_t)acc[mf][nf][r];
                else
                    ((float*)Cout)[(size_t)row * N + col] = acc[mf][nf][r];
            }
}

// --------- fused RMSNorm + RoPE in-place on f16 qkv[B*S][3][16][128] ---------
__global__ __launch_bounds__(256) void rmsrope_f16(f16_t* __restrict__ qkv,
                                                   const float* __restrict__ pe,
                                                   const float* __restrict__ qs,
                                                   const float* __restrict__ qb,
                                                   const float* __restrict__ ks,
                                                   const float* __restrict__ kb)
{
    const int unit = blockIdx.x * 4 + (threadIdx.x >> 6);
    const int l = threadIdx.x & 63;
    const int bs = unit >> 5, h = (unit >> 1) & 15, comp = unit & 1;
    f16_t* base = qkv + ((size_t)bs * 3 + comp) * 2048 + h * 128;
    const float* sc = comp ? ks : qs;
    const float* bi = comp ? kb : qb;

    f16x2 u = *(const f16x2*)(base + 2 * l);
    float u0 = (float)u[0], u1 = (float)u[1];
    float ss = u0 * u0 + u1 * u1;
#pragma unroll
    for (int o = 32; o; o >>= 1) ss += __shfl_xor(ss, o);
    float inv = rsqrtf(ss * (1.f / 128.f) + 1e-6f);

    float2 scv = *(const float2*)(sc + 2 * l);
    float2 biv = *(const float2*)(bi + 2 * l);
    float a = u0 * inv * scv.x + biv.x;
    float c = u1 * inv * scv.y + biv.y;
    float4 p4 = *(const float4*)(pe + (size_t)bs * 256 + l * 4);
    f16x2 o = {(f16_t)(p4.x * a + p4.y * c), (f16_t)(p4.z * a + p4.w * c)};
    *(f16x2*)(base + 2 * l) = o;
}

// ---------------- flash attention: 4 waves x 32 q-rows, KVBLK=64 ----------------
__global__ __launch_bounds__(256) void attn_f16(const f16_t* __restrict__ qkv,
                                                f16_t* __restrict__ out)
{
    __shared__ f16_t Kl[2][64 * 128];
    __shared__ f16_t Vt[128 * 72];
    const int tid = threadIdx.x, lane = tid & 63, wave = tid >> 6;
    const int lh = lane >> 4, li = lane & 15;
    const int bidx = blockIdx.x;
    const int bh = bidx & 63;
    const int qt = bidx >> 6;
    const int h = bh & 15, b = bh >> 4;
    const size_t seqbase = (size_t)b * 1024;
    const float SCALE = 0.08838834764831845f;

    const int qbase = qt * 128 + wave * 32;
    f16x8 qreg[2][4];
#pragma unroll
    for (int qf = 0; qf < 2; ++qf) {
        const f16_t* qp = qkv + (seqbase + qbase + qf * 16 + li) * 6144 + h * 128;
#pragma unroll
        for (int c = 0; c < 4; ++c) {
            f16x8 v = *(const f16x8*)(qp + c * 32 + lh * 8);
#pragma unroll
            for (int j = 0; j < 8; ++j) v[j] = (f16_t)((float)v[j] * SCALE);
            qreg[qf][c] = v;
        }
    }

    f32x4 oacc[2][8];
#pragma unroll
    for (int qf = 0; qf < 2; ++qf)
#pragma unroll
        for (int dt = 0; dt < 8; ++dt) oacc[qf][dt] = (f32x4){0.f, 0.f, 0.f, 0.f};
    float mrun[2] = {-1e30f, -1e30f}, lrun[2] = {0.f, 0.f};

    const int vd0 = (tid & 31) * 4;
    const int vk0 = (tid >> 5) * 8;
    f16x4 vreg[8];

#define STAGE_K(t, buf)                                                            \
    do {                                                                           \
        _Pragma("unroll")                                                          \
        for (int it = 0; it < 4; ++it) {                                           \
            const int c_ = it * 256 + tid;                                         \
            const int row_ = c_ >> 4, cc_ = c_ & 15;                               \
            const f16_t* src_ = qkv + (seqbase + (t) * 64 + row_) * 6144 + 2048 +  \
                                h * 128 + ((cc_ ^ (row_ & 7)) << 3);               \
            GLOAD_LDS16(src_, (char*)&Kl[buf][0] + (it * 256 + wave * 64) * 16);   \
        }                                                                          \
    } while (0)

#define LOAD_V(t)                                                                  \
    do {                                                                           \
        _Pragma("unroll")                                                          \
        for (int r_ = 0; r_ < 8; ++r_)                                             \
            vreg[r_] = *(const f16x4*)(qkv + (seqbase + (t) * 64 + vk0 + r_) *     \
                                       6144 + 4096 + h * 128 + vd0);               \
    } while (0)

    STAGE_K(0, 0);
    LOAD_V(0);

    for (int t = 0; t < 16; ++t) {
        const int buf = t & 1;
        __syncthreads();

#pragma unroll
        for (int dd = 0; dd < 4; ++dd) {
            f16x8 w;
#pragma unroll
            for (int r = 0; r < 8; ++r) w[r] = vreg[r][dd];
            *(f16x8*)&Vt[(vd0 + dd) * 72 + vk0] = w;
        }
        __syncthreads();

        if (t < 15) {
            STAGE_K(t + 1, buf ^ 1);
            LOAD_V(t + 1);
        }

        float s[2][16];
#pragma unroll
        for (int kvt = 0; kvt < 4; ++kvt) {
            f32x4 a0 = (f32x4){0.f, 0.f, 0.f, 0.f}, a1 = a0;
#pragma unroll
            for (int c = 0; c < 4; ++c) {
                const int kvrow = kvt * 16 + li;
                f16x8 kf = *(const f16x8*)&Kl[buf][kvrow * 128 +
                                                   (((c * 4 + lh) ^ (li & 7)) << 3)];
                a0 = __builtin_amdgcn_mfma_f32_16x16x32_f16(kf, qreg[0][c], a0, 0, 0, 0);
                a1 = __builtin_amdgcn_mfma_f32_16x16x32_f16(kf, qreg[1][c], a1, 0, 0, 0);
            }
#pragma unroll
            for (int r = 0; r < 4; ++r) { s[0][kvt * 4 + r] = a0[r]; s[1][kvt * 4 + r] = a1[r]; }
        }

        float pmax[2];
#pragma unroll
        for (int qf = 0; qf < 2; ++qf) {
            float mx = s[qf][0];
#pragma unroll
            for (int i = 1; i < 16; ++i) mx = fmaxf(mx, s[qf][i]);
            mx = fmaxf(mx, __shfl_xor(mx, 16));
            mx = fmaxf(mx, __shfl_xor(mx, 32));
            pmax[qf] = mx;
        }
        const bool defer = __all((pmax[0] - mrun[0] <= 8.f) && (pmax[1] - mrun[1] <= 8.f));
        if (!defer) {
#pragma unroll
            for (int qf = 0; qf < 2; ++qf) {
                const float mn = fmaxf(mrun[qf], pmax[qf]);
                const float alpha = __expf(mrun[qf] - mn);
                lrun[qf] *= alpha;
                mrun[qf] = mn;
                float ar[4];
#pragma unroll
                for (int r = 0; r < 4; ++r) ar[r] = __shfl(alpha, 4 * lh + r);
#pragma unroll
                for (int dt = 0; dt < 8; ++dt)
#pragma unroll
                    for (int r = 0; r < 4; ++r) oacc[qf][dt][r] *= ar[r];
            }
        }

        f16x8 pa[2][2];
#pragma unroll
        for (int qf = 0; qf < 2; ++qf) {
            float ls = 0.f;
            float p[16];
#pragma unroll
            for (int i = 0; i < 16; ++i) { p[i] = __expf(s[qf][i] - mrun[qf]); ls += p[i]; }
            ls += __shfl_xor(ls, 16);
            ls += __shfl_xor(ls, 32);
            lrun[qf] += ls;
#pragma unroll
            for (int hf = 0; hf < 2; ++hf)
#pragma unroll
                for (int j = 0; j < 8; ++j)
                    pa[qf][hf][j] = (f16_t)p[(2 * hf + (j >> 2)) * 4 + (j & 3)];
        }

#pragma unroll
        for (int dt = 0; dt < 8; ++dt) {
            const int drow = dt * 16 + li;
            f16x4 v0 = *(const f16x4*)&Vt[drow * 72 + 4 * lh];
            f16x4 v1 = *(const f16x4*)&Vt[drow * 72 + 16 + 4 * lh];
            f16x4 v2 = *(const f16x4*)&Vt[drow * 72 + 32 + 4 * lh];
            f16x4 v3 = *(const f16x4*)&Vt[drow * 72 + 48 + 4 * lh];
            f16x8 vf0 = {v0[0], v0[1], v0[2], v0[3], v1[0], v1[1], v1[2], v1[3]};
            f16x8 vf1 = {v2[0], v2[1], v2[2], v2[3], v3[0], v3[1], v3[2], v3[3]};
#pragma unroll
            for (int qf = 0; qf < 2; ++qf) {
                oacc[qf][dt] = __builtin_amdgcn_mfma_f32_16x16x32_f16(pa[qf][0], vf0,
                                                                      oacc[qf][dt], 0, 0, 0);
                oacc[qf][dt] = __builtin_amdgcn_mfma_f32_16x16x32_f16(pa[qf][1], vf1,
                                                                      oacc[qf][dt], 0, 0, 0);
            }
        }
    }

#pragma unroll
    for (int qf = 0; qf < 2; ++qf) {
        const float inv = 1.f / lrun[qf];
        float ir[4];
#pragma unroll
        for (int r = 0; r < 4; ++r) ir[r] = __shfl(inv, 4 * lh + r);
#pragma unroll
        for (int dt = 0; dt < 8; ++dt)
#pragma unroll
            for (int r = 0; r < 4; ++r) {
                const int row = qbase + qf * 16 + 4 * lh + r;
                out[(seqbase + row) * 2048 + h * 128 + dt * 16 + li] =
                    (f16_t)(oacc[qf][dt][r] * ir[r]);
            }
    }
#undef STAGE_K
#undef LOAD_V
}

extern "C" void kernel_launch(void* const* d_in, const int* in_sizes, int n_in,
                              void* d_out, int out_size, void* d_ws, size_t ws_size,
                              hipStream_t stream) {
    const float* x       = (const float*)d_in[0];
    const float* pe      = (const float*)d_in[1];
    const float* w_qkv   = (const float*)d_in[2];
    const float* w_o     = (const float*)d_in[3];
    const float* q_scale = (const float*)d_in[4];
    const float* q_bias  = (const float*)d_in[5];
    const float* k_scale = (const float*)d_in[6];
    const float* k_bias  = (const float*)d_in[7];
    float* out = (float*)d_out;

    char* ws = (char*)d_ws;
    f16_t* x16    = (f16_t*)(ws);
    f16_t* wqkvT  = (f16_t*)(ws + 16777216);
    f16_t* woT    = (f16_t*)(ws + 41943040);
    f16_t* qkv16  = (f16_t*)(ws + 50331648);
    f16_t* attn16 = (f16_t*)(ws + 100663296);

    // allow >64KB dynamic LDS (idempotent, host-side only — graph-capture safe)
    hipFuncSetAttribute((const void*)&gemm_v3<256, 2, 4, 1>,
                        hipFuncAttributeMaxDynamicSharedMemorySize, 131072);
    hipFuncSetAttribute((const void*)&gemm_v3<128, 4, 2, 0>,
                        hipFuncAttributeMaxDynamicSharedMemorySize, 98304);

    conv_f16<<<4096, 256, 0, stream>>>(x, x16);
    transpose_f16<<<dim3(6144 / 32, 2048 / 32), 256, 0, stream>>>(w_qkv, wqkvT, 2048, 6144);
    transpose_f16<<<dim3(2048 / 32, 2048 / 32), 256, 0, stream>>>(w_o, woT, 2048, 2048);

    // qkv = x @ w_qkv: M=4096 N=6144 K=2048; grid 16x24=384 (%8==0)
    gemm_v3<256, 2, 4, 1><<<384, 512, 131072, stream>>>(x16, wqkvT, qkv16,
                                                        4096, 6144, 2048, 24);

    rmsrope_f16<<<32768, 256, 0, stream>>>(qkv16, pe, q_scale, q_bias, k_scale, k_bias);

    attn_f16<<<512, 256, 0, stream>>>(qkv16, attn16);

    // out = attn @ w_o: M=4096 N=2048 K=2048; grid 16x16=256 (exactly 1 round)
    gemm_v3<128, 4, 2, 0><<<256, 512, 98304, stream>>>(attn16, woT, out,
                                                       4096, 2048, 2048, 16);
}

// Round 6
// 278.202 us; speedup vs baseline: 10.8026x; 1.1106x over previous
//
#include <hip/hip_runtime.h>
#include <hip/hip_bf16.h>

typedef _Float16 f16_t;
typedef _Float16 f16x2 __attribute__((ext_vector_type(2)));
typedef _Float16 f16x4 __attribute__((ext_vector_type(4)));
typedef _Float16 f16x8 __attribute__((ext_vector_type(8)));
typedef float f32x4 __attribute__((ext_vector_type(4)));

#define GLOAD_LDS16(gp, lp)                                                        \
  __builtin_amdgcn_global_load_lds(                                                \
      (const __attribute__((address_space(1))) void*)(gp),                         \
      (__attribute__((address_space(3))) void*)(lp), 16, 0, 0)

template<int N> __device__ __forceinline__ void vmwait() {
    if constexpr (N == 0)      asm volatile("s_waitcnt vmcnt(0)" ::: "memory");
    else if constexpr (N == 3) asm volatile("s_waitcnt vmcnt(3)" ::: "memory");
    else if constexpr (N == 5) asm volatile("s_waitcnt vmcnt(5)" ::: "memory");
    else if constexpr (N == 6) asm volatile("s_waitcnt vmcnt(6)" ::: "memory");
    else                       asm volatile("s_waitcnt vmcnt(0)" ::: "memory");
}

// ---------------- f32 -> f16 elementwise convert (8 elems/thread) ----------------
__global__ __launch_bounds__(256) void conv_f16(const float* __restrict__ in,
                                                f16_t* __restrict__ out)
{
    int i = blockIdx.x * 256 + threadIdx.x;
    float4 a = *(const float4*)&in[(size_t)i * 8];
    float4 b = *(const float4*)&in[(size_t)i * 8 + 4];
    f16x8 o = {(f16_t)a.x, (f16_t)a.y, (f16_t)a.z, (f16_t)a.w,
               (f16_t)b.x, (f16_t)b.y, (f16_t)b.z, (f16_t)b.w};
    *(f16x8*)&out[(size_t)i * 8] = o;
}

// ------------- f32 [R][C] -> f16 transposed [C][R], 32x32 LDS tiles -------------
__global__ __launch_bounds__(256) void transpose_f16(const float* __restrict__ in,
                                                     f16_t* __restrict__ out,
                                                     int R, int C)
{
    __shared__ float t[32][33];
    const int tr = blockIdx.y, tc = blockIdx.x;
    const int r = threadIdx.x >> 3, c4 = (threadIdx.x & 7) * 4;
    float4 v = *(const float4*)&in[(size_t)(tr * 32 + r) * C + tc * 32 + c4];
    t[r][c4 + 0] = v.x; t[r][c4 + 1] = v.y; t[r][c4 + 2] = v.z; t[r][c4 + 3] = v.w;
    __syncthreads();
    f16x4 o = {(f16_t)t[c4 + 0][r], (f16_t)t[c4 + 1][r],
               (f16_t)t[c4 + 2][r], (f16_t)t[c4 + 3][r]};
    *(f16x4*)&out[(size_t)(tc * 32 + r) * R + tr * 32 + c4] = o;
}

// ------------- f16 MFMA GEMM v4: C = A[M][K] @ BT[N][K]^T -------------
// BM x BN tile, BK=32, 512 threads (8 waves 2x4, wave tile WMT x WNT).
// 3 LDS buffers, depth-2 prefetch, ONE barrier per K-tile (3-buf makes the
// overwrite target 2 iters stale), counted vmcnt (never 0 until drain),
// T2 16B-unit XOR swizzle (linear LDS dest, pre-swizzled global source),
// column-major XCD swizzle so each XCD's B strip stays L2-resident.
template<int BM, int BN, int GY, int F16OUT>
__global__ __launch_bounds__(512, 2) void gemm_v4(const f16_t* __restrict__ A,
                                                  const f16_t* __restrict__ BT,
                                                  void* __restrict__ Cout,
                                                  int M, int N, int K)
{
    extern __shared__ char smem[];
    constexpr int WMT = BM / 2, WNT = BN / 4;
    constexpr int MF = WMT / 16, NF = WNT / 16, MFH = MF / 2, NFH = NF / 2;
    constexpr int ALI = BM / 128, BLI = BN / 128;   // stage iters (512 thr each)
    constexpr int L = ALI + BLI;                    // gloads per wave per tile
    constexpr int ABUFB = BM * 64, BBUFB = BN * 64; // bytes per K-tile buffer

    const int tid = threadIdx.x, lane = tid & 63, wave = tid >> 6;
    const int lh = lane >> 4, li = lane & 15;
    const int wr = wave >> 2, wc = wave & 3;

    const int nwg = gridDim.x, bid = blockIdx.x;
    const int swz = (bid & 7) * (nwg >> 3) + (bid >> 3);
    const int by = swz % GY, bx = swz / GY;         // column-major: bx strip per XCD

    const size_t bmK = (size_t)(by * BM) * K;
    const size_t bnK = (size_t)(bx * BN) * K;
    const int NT = K >> 5;

    f32x4 acc[MF][NF];
#pragma unroll
    for (int i = 0; i < MF; ++i)
#pragma unroll
        for (int j = 0; j < NF; ++j) acc[i][j] = (f32x4){0.f, 0.f, 0.f, 0.f};

    // stage K-tile t into buffer b: chunk c: row=c>>2, lds unit u=c&3,
    // global unit gu = u ^ ((row>>1)&3); LDS linear (wave base + lane*16).
#define STAGE(t, b)                                                                \
    do {                                                                           \
        const int kof_ = (t) << 5;                                                 \
        char* Ab_ = smem + (b) * ABUFB;                                            \
        char* Bb_ = smem + 3 * ABUFB + (b) * BBUFB;                                \
        _Pragma("unroll")                                                          \
        for (int i_ = 0; i_ < ALI; ++i_) {                                         \
            const int c_ = i_ * 512 + tid;                                         \
            const int row_ = c_ >> 2;                                              \
            const int gu_ = (c_ & 3) ^ ((row_ >> 1) & 3);                          \
            GLOAD_LDS16(A + bmK + (size_t)row_ * K + kof_ + gu_ * 8,               \
                        Ab_ + (i_ * 512 + wave * 64) * 16);                        \
        }                                                                          \
        _Pragma("unroll")                                                          \
        for (int i_ = 0; i_ < BLI; ++i_) {                                         \
            const int c_ = i_ * 512 + tid;                                         \
            const int row_ = c_ >> 2;                                              \
            const int gu_ = (c_ & 3) ^ ((row_ >> 1) & 3);                          \
            GLOAD_LDS16(BT + bnK + (size_t)row_ * K + kof_ + gu_ * 8,              \
                        Bb_ + (i_ * 512 + wave * 64) * 16);                        \
        }                                                                          \
    } while (0)

    STAGE(0, 0);
    STAGE(1, 1);

    const int runit = (lh ^ ((li >> 1) & 3)) << 3;  // swizzled 8-f16 unit offset

    int rb = 0;  // buffer holding tile t
    for (int t = 0; t < NT; ++t) {
        if (t + 1 < NT) vmwait<L>();   // tile t landed (t+1 stays in flight)
        else            vmwait<0>();
        __builtin_amdgcn_s_barrier();  // all waves' tile-t loads visible;
                                       // all waves done reading buf (t-1)%3
        if (t + 2 < NT) {
            const int sb = rb ? rb - 1 : 2;   // (t+2)%3
            STAGE(t + 2, sb);
        }
        __builtin_amdgcn_sched_barrier(0);

        const f16_t* Ab = (const f16_t*)(smem + rb * ABUFB);
        const f16_t* Bb = (const f16_t*)(smem + 3 * ABUFB + rb * BBUFB);
        f16x8 af[MFH], bf[NFH];
#pragma unroll
        for (int bh = 0; bh < 2; ++bh) {
#pragma unroll
            for (int j = 0; j < NFH; ++j)
                bf[j] = *(const f16x8*)(Bb + (wc * WNT + (bh * NFH + j) * 16 + li) * 32
                                        + runit);
#pragma unroll
            for (int ah = 0; ah < 2; ++ah) {
#pragma unroll
                for (int j = 0; j < MFH; ++j)
                    af[j] = *(const f16x8*)(Ab + (wr * WMT + (ah * MFH + j) * 16 + li) * 32
                                            + runit);
                __builtin_amdgcn_s_setprio(1);
#pragma unroll
                for (int i = 0; i < MFH; ++i)
#pragma unroll
                    for (int j = 0; j < NFH; ++j)
                        acc[ah * MFH + i][bh * NFH + j] =
                            __builtin_amdgcn_mfma_f32_16x16x32_f16(
                                af[i], bf[j], acc[ah * MFH + i][bh * NFH + j], 0, 0, 0);
                __builtin_amdgcn_s_setprio(0);
                __builtin_amdgcn_sched_barrier(0);
            }
        }
        rb = (rb == 2) ? 0 : rb + 1;
    }
#undef STAGE

    // C/D layout: col = lane&15, row = (lane>>4)*4 + reg
#pragma unroll
    for (int mf = 0; mf < MF; ++mf)
#pragma unroll
        for (int nf = 0; nf < NF; ++nf)
#pragma unroll
            for (int r = 0; r < 4; ++r) {
                const int row = by * BM + wr * WMT + mf * 16 + lh * 4 + r;
                const int col = bx * BN + wc * WNT + nf * 16 + li;
                if (F16OUT)
                    ((f16_t*)Cout)[(size_t)row * N + col] = (f16_t)acc[mf][nf][r];
                else
                    ((float*)Cout)[(size_t)row * N + col] = acc[mf][nf][r];
            }
}

// --------- fused RMSNorm + RoPE in-place on f16 qkv[B*S][3][16][128] ---------
__global__ __launch_bounds__(256) void rmsrope_f16(f16_t* __restrict__ qkv,
                                                   const float* __restrict__ pe,
                                                   const float* __restrict__ qs,
                                                   const float* __restrict__ qb,
                                                   const float* __restrict__ ks,
                                                   const float* __restrict__ kb)
{
    const int unit = blockIdx.x * 4 + (threadIdx.x >> 6);
    const int l = threadIdx.x & 63;
    const int bs = unit >> 5, h = (unit >> 1) & 15, comp = unit & 1;
    f16_t* base = qkv + ((size_t)bs * 3 + comp) * 2048 + h * 128;
    const float* sc = comp ? ks : qs;
    const float* bi = comp ? kb : qb;

    f16x2 u = *(const f16x2*)(base + 2 * l);
    float u0 = (float)u[0], u1 = (float)u[1];
    float ss = u0 * u0 + u1 * u1;
#pragma unroll
    for (int o = 32; o; o >>= 1) ss += __shfl_xor(ss, o);
    float inv = rsqrtf(ss * (1.f / 128.f) + 1e-6f);

    float2 scv = *(const float2*)(sc + 2 * l);
    float2 biv = *(const float2*)(bi + 2 * l);
    float a = u0 * inv * scv.x + biv.x;
    float c = u1 * inv * scv.y + biv.y;
    float4 p4 = *(const float4*)(pe + (size_t)bs * 256 + l * 4);
    f16x2 o = {(f16_t)(p4.x * a + p4.y * c), (f16_t)(p4.z * a + p4.w * c)};
    *(f16x2*)(base + 2 * l) = o;
}

// ---------------- flash attention: 4 waves x 32 q-rows, KVBLK=64 ----------------
__global__ __launch_bounds__(256) void attn_f16(const f16_t* __restrict__ qkv,
                                                f16_t* __restrict__ out)
{
    __shared__ f16_t Kl[2][64 * 128];
    __shared__ f16_t Vt[128 * 72];
    const int tid = threadIdx.x, lane = tid & 63, wave = tid >> 6;
    const int lh = lane >> 4, li = lane & 15;
    const int bidx = blockIdx.x;
    const int bh = bidx & 63;
    const int qt = bidx >> 6;
    const int h = bh & 15, b = bh >> 4;
    const size_t seqbase = (size_t)b * 1024;
    const float SCALE = 0.08838834764831845f;

    const int qbase = qt * 128 + wave * 32;
    f16x8 qreg[2][4];
#pragma unroll
    for (int qf = 0; qf < 2; ++qf) {
        const f16_t* qp = qkv + (seqbase + qbase + qf * 16 + li) * 6144 + h * 128;
#pragma unroll
        for (int c = 0; c < 4; ++c) {
            f16x8 v = *(const f16x8*)(qp + c * 32 + lh * 8);
#pragma unroll
            for (int j = 0; j < 8; ++j) v[j] = (f16_t)((float)v[j] * SCALE);
            qreg[qf][c] = v;
        }
    }

    f32x4 oacc[2][8];
#pragma unroll
    for (int qf = 0; qf < 2; ++qf)
#pragma unroll
        for (int dt = 0; dt < 8; ++dt) oacc[qf][dt] = (f32x4){0.f, 0.f, 0.f, 0.f};
    float mrun[2] = {-1e30f, -1e30f}, lrun[2] = {0.f, 0.f};

    const int vd0 = (tid & 31) * 4;
    const int vk0 = (tid >> 5) * 8;
    f16x4 vreg[8];

#define STAGE_K(t, buf)                                                            \
    do {                                                                           \
        _Pragma("unroll")                                                          \
        for (int it = 0; it < 4; ++it) {                                           \
            const int c_ = it * 256 + tid;                                         \
            const int row_ = c_ >> 4, cc_ = c_ & 15;                               \
            const f16_t* src_ = qkv + (seqbase + (t) * 64 + row_) * 6144 + 2048 +  \
                                h * 128 + ((cc_ ^ (row_ & 7)) << 3);               \
            GLOAD_LDS16(src_, (char*)&Kl[buf][0] + (it * 256 + wave * 64) * 16);   \
        }                                                                          \
    } while (0)

#define LOAD_V(t)                                                                  \
    do {                                                                           \
        _Pragma("unroll")                                                          \
        for (int r_ = 0; r_ < 8; ++r_)                                             \
            vreg[r_] = *(const f16x4*)(qkv + (seqbase + (t) * 64 + vk0 + r_) *     \
                                       6144 + 4096 + h * 128 + vd0);               \
    } while (0)

    STAGE_K(0, 0);
    LOAD_V(0);

    for (int t = 0; t < 16; ++t) {
        const int buf = t & 1;
        __syncthreads();

#pragma unroll
        for (int dd = 0; dd < 4; ++dd) {
            f16x8 w;
#pragma unroll
            for (int r = 0; r < 8; ++r) w[r] = vreg[r][dd];
            *(f16x8*)&Vt[(vd0 + dd) * 72 + vk0] = w;
        }
        __syncthreads();

        if (t < 15) {
            STAGE_K(t + 1, buf ^ 1);
            LOAD_V(t + 1);
        }

        float s[2][16];
#pragma unroll
        for (int kvt = 0; kvt < 4; ++kvt) {
            f32x4 a0 = (f32x4){0.f, 0.f, 0.f, 0.f}, a1 = a0;
#pragma unroll
            for (int c = 0; c < 4; ++c) {
                const int kvrow = kvt * 16 + li;
                f16x8 kf = *(const f16x8*)&Kl[buf][kvrow * 128 +
                                                   (((c * 4 + lh) ^ (li & 7)) << 3)];
                a0 = __builtin_amdgcn_mfma_f32_16x16x32_f16(kf, qreg[0][c], a0, 0, 0, 0);
                a1 = __builtin_amdgcn_mfma_f32_16x16x32_f16(kf, qreg[1][c], a1, 0, 0, 0);
            }
#pragma unroll
            for (int r = 0; r < 4; ++r) { s[0][kvt * 4 + r] = a0[r]; s[1][kvt * 4 + r] = a1[r]; }
        }

        float pmax[2];
#pragma unroll
        for (int qf = 0; qf < 2; ++qf) {
            float mx = s[qf][0];
#pragma unroll
            for (int i = 1; i < 16; ++i) mx = fmaxf(mx, s[qf][i]);
            mx = fmaxf(mx, __shfl_xor(mx, 16));
            mx = fmaxf(mx, __shfl_xor(mx, 32));
            pmax[qf] = mx;
        }
        const bool defer = __all((pmax[0] - mrun[0] <= 8.f) && (pmax[1] - mrun[1] <= 8.f));
        if (!defer) {
#pragma unroll
            for (int qf = 0; qf < 2; ++qf) {
                const float mn = fmaxf(mrun[qf], pmax[qf]);
                const float alpha = __expf(mrun[qf] - mn);
                lrun[qf] *= alpha;
                mrun[qf] = mn;
                float ar[4];
#pragma unroll
                for (int r = 0; r < 4; ++r) ar[r] = __shfl(alpha, 4 * lh + r);
#pragma unroll
                for (int dt = 0; dt < 8; ++dt)
#pragma unroll
                    for (int r = 0; r < 4; ++r) oacc[qf][dt][r] *= ar[r];
            }
        }

        f16x8 pa[2][2];
#pragma unroll
        for (int qf = 0; qf < 2; ++qf) {
            float ls = 0.f;
            float p[16];
#pragma unroll
            for (int i = 0; i < 16; ++i) { p[i] = __expf(s[qf][i] - mrun[qf]); ls += p[i]; }
            ls += __shfl_xor(ls, 16);
            ls += __shfl_xor(ls, 32);
            lrun[qf] += ls;
#pragma unroll
            for (int hf = 0; hf < 2; ++hf)
#pragma unroll
                for (int j = 0; j < 8; ++j)
                    pa[qf][hf][j] = (f16_t)p[(2 * hf + (j >> 2)) * 4 + (j & 3)];
        }

#pragma unroll
        for (int dt = 0; dt < 8; ++dt) {
            const int drow = dt * 16 + li;
            f16x4 v0 = *(const f16x4*)&Vt[drow * 72 + 4 * lh];
            f16x4 v1 = *(const f16x4*)&Vt[drow * 72 + 16 + 4 * lh];
            f16x4 v2 = *(const f16x4*)&Vt[drow * 72 + 32 + 4 * lh];
            f16x4 v3 = *(const f16x4*)&Vt[drow * 72 + 48 + 4 * lh];
            f16x8 vf0 = {v0[0], v0[1], v0[2], v0[3], v1[0], v1[1], v1[2], v1[3]};
            f16x8 vf1 = {v2[0], v2[1], v2[2], v2[3], v3[0], v3[1], v3[2], v3[3]};
#pragma unroll
            for (int qf = 0; qf < 2; ++qf) {
                oacc[qf][dt] = __builtin_amdgcn_mfma_f32_16x16x32_f16(pa[qf][0], vf0,
                                                                      oacc[qf][dt], 0, 0, 0);
                oacc[qf][dt] = __builtin_amdgcn_mfma_f32_16x16x32_f16(pa[qf][1], vf1,
                                                                      oacc[qf][dt], 0, 0, 0);
            }
        }
    }

#pragma unroll
    for (int qf = 0; qf < 2; ++qf) {
        const float inv = 1.f / lrun[qf];
        float ir[4];
#pragma unroll
        for (int r = 0; r < 4; ++r) ir[r] = __shfl(inv, 4 * lh + r);
#pragma unroll
        for (int dt = 0; dt < 8; ++dt)
#pragma unroll
            for (int r = 0; r < 4; ++r) {
                const int row = qbase + qf * 16 + 4 * lh + r;
                out[(seqbase + row) * 2048 + h * 128 + dt * 16 + li] =
                    (f16_t)(oacc[qf][dt][r] * ir[r]);
            }
    }
#undef STAGE_K
#undef LOAD_V
}

extern "C" void kernel_launch(void* const* d_in, const int* in_sizes, int n_in,
                              void* d_out, int out_size, void* d_ws, size_t ws_size,
                              hipStream_t stream) {
    const float* x       = (const float*)d_in[0];
    const float* pe      = (const float*)d_in[1];
    const float* w_qkv   = (const float*)d_in[2];
    const float* w_o     = (const float*)d_in[3];
    const float* q_scale = (const float*)d_in[4];
    const float* q_bias  = (const float*)d_in[5];
    const float* k_scale = (const float*)d_in[6];
    const float* k_bias  = (const float*)d_in[7];
    float* out = (float*)d_out;

    char* ws = (char*)d_ws;
    f16_t* x16    = (f16_t*)(ws);
    f16_t* wqkvT  = (f16_t*)(ws + 16777216);
    f16_t* woT    = (f16_t*)(ws + 41943040);
    f16_t* qkv16  = (f16_t*)(ws + 50331648);
    f16_t* attn16 = (f16_t*)(ws + 100663296);

    hipFuncSetAttribute((const void*)&gemm_v4<256, 384, 16, 1>,
                        hipFuncAttributeMaxDynamicSharedMemorySize, 122880);
    hipFuncSetAttribute((const void*)&gemm_v4<128, 256, 32, 0>,
                        hipFuncAttributeMaxDynamicSharedMemorySize, 73728);

    conv_f16<<<4096, 256, 0, stream>>>(x, x16);
    transpose_f16<<<dim3(6144 / 32, 2048 / 32), 256, 0, stream>>>(w_qkv, wqkvT, 2048, 6144);
    transpose_f16<<<dim3(2048 / 32, 2048 / 32), 256, 0, stream>>>(w_o, woT, 2048, 2048);

    // qkv = x @ w_qkv: M=4096 N=6144 K=2048; tiles 256x384, grid 16x16=256 (1 round)
    gemm_v4<256, 384, 16, 1><<<256, 512, 122880, stream>>>(x16, wqkvT, qkv16,
                                                           4096, 6144, 2048);

    rmsrope_f16<<<32768, 256, 0, stream>>>(qkv16, pe, q_scale, q_bias, k_scale, k_bias);

    attn_f16<<<512, 256, 0, stream>>>(qkv16, attn16);

    // out = attn @ w_o: M=4096 N=2048 K=2048; tiles 128x256, grid 32x8=256 (1 round)
    gemm_v4<128, 256, 32, 0><<<256, 512, 73728, stream>>>(attn16, woT, out,
                                                          4096, 2048, 2048);
}